// Round 14
// baseline (665.529 us; speedup 1.0000x reference)
//
#include <hip/hip_runtime.h>
#include <hip/hip_bf16.h>

#define DEMB 64
typedef unsigned short u16;
typedef float f32x2 __attribute__((ext_vector_type(2)));

__device__ __forceinline__ unsigned f2bf(float f) {
    union { float f; unsigned int i; } c; c.f = f;
    unsigned int r = c.i + 0x7FFF + ((c.i >> 16) & 1);
    return r >> 16;
}
__device__ __forceinline__ float lo16(unsigned int w) {
    union { unsigned int i; float f; } c; c.i = w << 16; return c.f;
}
__device__ __forceinline__ float hi16(unsigned int w) {
    union { unsigned int i; float f; } c; c.i = w & 0xFFFF0000u; return c.f;
}

// odd 7th-order minimax tanh on [-1.02, 1.02], abs err <= ~3e-4
__device__ __forceinline__ float ptanh5(float a) {
    float a2 = a * a;
    float t = fmaf(a2, -0.030095f, 0.124066f);
    t = fmaf(a2, t, -0.332377f);
    t = fmaf(a2, t, 1.0f);
    return a * t;
}

__global__ void init_A_kernel(float4* __restrict__ A, int E) {
    int e = blockIdx.x * blockDim.x + threadIdx.x;
    if (e < E) A[e] = make_float4(1.f, 1.f, 1.f, 1.f);
}

__global__ void concat_copy_kernel(const float* __restrict__ u, const float* __restrict__ it,
                                   float* __restrict__ x, float* __restrict__ acc,
                                   int nu_elems, int total) {
    int i = blockIdx.x * blockDim.x + threadIdx.x;
    if (i >= total) return;
    float v = (i < nu_elems) ? u[i] : it[i - nu_elems];
    x[i] = v;
    acc[i] = v;
}

// ============ CSR build: deterministic histogram radix (R9-proven) ============
__global__ void hist_kernel(const int* __restrict__ h, int* __restrict__ ghist,
                            int E, int EPB, int NB) {
    __shared__ int bins[1024];
    int b = blockIdx.x, tid = threadIdx.x;
    for (int j = tid; j < NB; j += 256) bins[j] = 0;
    __syncthreads();
    int s = b * EPB, e = min(s + EPB, E);
    for (int k = s + tid; k < e; k += 256)
        atomicAdd(&bins[((unsigned)h[k]) >> 8], 1);
    __syncthreads();
    for (int j = tid; j < NB; j += 256) ghist[j * gridDim.x + b] = bins[j];
}

__global__ void btot_kernel(const int* __restrict__ ghist, int* __restrict__ btot) {
    __shared__ int s[256];
    int j = blockIdx.x, tid = threadIdx.x;
    s[tid] = ghist[j * 256 + tid];
    __syncthreads();
    for (int o = 128; o >= 1; o >>= 1) {
        if (tid < o) s[tid] += s[tid + o];
        __syncthreads();
    }
    if (tid == 0) btot[j] = s[0];
}

__global__ void bscan_kernel(const int* __restrict__ btot, int* __restrict__ bbase,
                             int NB, int E) {
    __shared__ int s[1024];
    int tid = threadIdx.x;
    int v = (tid < NB) ? btot[tid] : 0;
    s[tid] = v;
    __syncthreads();
    for (int o = 1; o < 1024; o <<= 1) {
        int a = (tid >= o) ? s[tid - o] : 0;
        __syncthreads();
        s[tid] += a;
        __syncthreads();
    }
    if (tid < NB) bbase[tid] = s[tid] - v;
    if (tid == 0) bbase[NB] = E;
}

__global__ void bofs_kernel(int* __restrict__ ghist, const int* __restrict__ bbase) {
    __shared__ int s[256];
    int j = blockIdx.x, tid = threadIdx.x;
    int v = ghist[j * 256 + tid];
    s[tid] = v;
    __syncthreads();
    for (int o = 1; o < 256; o <<= 1) {
        int a = (tid >= o) ? s[tid - o] : 0;
        __syncthreads();
        s[tid] += a;
        __syncthreads();
    }
    ghist[j * 256 + tid] = bbase[j] + s[tid] - v;
}

__global__ void scatter_kernel(const int* __restrict__ h, const int* __restrict__ t,
                               const int* __restrict__ ghist, unsigned* __restrict__ stg,
                               int E, int EPB, int NB) {
    __shared__ int cur[1024];
    int b = blockIdx.x, tid = threadIdx.x;
    for (int j = tid; j < NB; j += 256) cur[j] = ghist[j * gridDim.x + b];
    __syncthreads();
    int s = b * EPB, e = min(s + EPB, E);
    for (int k = s + tid; k < e; k += 256) {
        unsigned hh = (unsigned)h[k];
        int pos = atomicAdd(&cur[hh >> 8], 1);
        stg[pos] = ((hh & 255u) << 18) | (unsigned)t[k];
    }
}

__global__ void finalize_kernel(const unsigned* __restrict__ stg, const int* __restrict__ bbase,
                                int* __restrict__ off, int* __restrict__ csr_t, int N, int E) {
    __shared__ int cnt[256];
    __shared__ int scn[256];
    int b = blockIdx.x, tid = threadIdx.x;
    int ebeg = bbase[b], eend = bbase[b + 1];
    cnt[tid] = 0;
    __syncthreads();
    for (int k = ebeg + tid; k < eend; k += 256)
        atomicAdd(&cnt[(stg[k] >> 18) & 255u], 1);
    __syncthreads();
    int v = cnt[tid];
    scn[tid] = v;
    __syncthreads();
    for (int o = 1; o < 256; o <<= 1) {
        int a = (tid >= o) ? scn[tid - o] : 0;
        __syncthreads();
        scn[tid] += a;
        __syncthreads();
    }
    int excl = scn[tid] - v;
    int gn = (b << 8) + tid;
    if (gn < N) off[gn] = ebeg + excl;
    if (b == 0 && tid == 0) off[N] = E;
    __syncthreads();
    cnt[tid] = excl;   // reuse as cursor
    __syncthreads();
    for (int k = ebeg + tid; k < eend; k += 256) {
        unsigned en = stg[k];
        int slot = atomicAdd(&cnt[(en >> 18) & 255u], 1);
        csr_t[ebeg + slot] = (int)(en & 0x3FFFFu);
    }
}

// bootstrap: prob=0.25 folded -> dcol0 = 0.5/sqrt(deg)
__global__ void dcol0_kernel(const int* __restrict__ off, float* __restrict__ dcol, int N) {
    int n = blockIdx.x * blockDim.x + threadIdx.x;
    if (n >= N) return;
    float v = 0.5f * rsqrtf((float)(off[n + 1] - off[n]));
    *(float4*)(dcol + (size_t)n * 4) = make_float4(v, v, v, v);
}

// ============ per-layer: xt[i] = (bf16(tanh(x/||x_f||)) << 16) | bf16(x)
__global__ void prep_kernel(const float* __restrict__ x, unsigned* __restrict__ xt, int total) {
    int i = blockIdx.x * blockDim.x + threadIdx.x;
    if (i >= total) return;
    float v = x[i];
    float s = v * v;
#pragma unroll
    for (int o = 8; o >= 1; o >>= 1) s += __shfl_xor(s, o);
    float nr = fmaxf(sqrtf(s), 1e-12f);
    unsigned tb = f2bf(ptanh5(v * __builtin_amdgcn_rcpf(nr)));
    xt[i] = (tb << 16) | f2bf(v);
}

// ============ fused message + routing + next-iteration softmax/dcol
// One 64-lane wave per node. lane l: g=l>>4 (edge slot), m=l&15 (col quad), f=m>>2.
// xt packs xs (lo16) + tail (hi16): loop1 fetches the lines (L2 miss), loop2
// re-reads the SAME lines (L2 hit). No register cache -> low VGPR, occupancy high.
// ACC: 0=none, 1=acc+=val, 2=acc=(acc+val)/3 (final mean)
template <bool UNI, bool WOUT, bool ROUTE, int ACC>
__global__ void message_kernel(const int* __restrict__ off, const int* __restrict__ csr_t,
                               float* __restrict__ Acsr, float* __restrict__ prob,
                               const unsigned* __restrict__ xt,
                               const float* __restrict__ dcol_in, float* __restrict__ dcol_out,
                               float* __restrict__ out, float* __restrict__ acc, int N) {
    int gid = blockIdx.x * blockDim.x + threadIdx.x;
    int n = gid >> 6;
    if (n >= N) return;
    int l = gid & 63;
    int g = l >> 4;
    int m = l & 15;
    unsigned f = (unsigned)(m >> 2);
    int s = off[n], e = off[n + 1];
    unsigned moff = (unsigned)(m << 2);   // u32 index within the 64-wide row

    f32x2 a01 = {0.f, 0.f}, a23 = {0.f, 0.f};

#pragma unroll 2
    for (int k = s; k < e; k += 8) {
        int e1 = k + g, e2 = e1 + 4;
        bool v1 = e1 < e, v2 = e2 < e;
        unsigned c1 = (unsigned)(v1 ? e1 : s);
        unsigned c2 = (unsigned)(v2 ? e2 : s);
        unsigned t1 = (unsigned)csr_t[c1];
        unsigned t2 = (unsigned)csr_t[c2];
        float p1, p2;
        if (UNI) {
            p1 = dcol_in[t1 * 4u + f];
            p2 = dcol_in[t2 * 4u + f];
        } else {
            p1 = prob[c1 * 4u + f] * dcol_in[t1 * 4u + f];
            p2 = prob[c2 * 4u + f] * dcol_in[t2 * 4u + f];
        }
        p1 = v1 ? p1 : 0.f;
        p2 = v2 ? p2 : 0.f;
        const uint4 w1 = *(const uint4*)(xt + (t1 << 6) + moff);
        const uint4 w2 = *(const uint4*)(xt + (t2 << 6) + moff);
        a01 += p1 * (f32x2){lo16(w1.x), lo16(w1.y)} + p2 * (f32x2){lo16(w2.x), lo16(w2.y)};
        a23 += p1 * (f32x2){lo16(w1.z), lo16(w1.w)} + p2 * (f32x2){lo16(w2.z), lo16(w2.w)};
    }

    float a0 = a01.x, a1 = a01.y, a2 = a23.x, a3 = a23.y;
    // combine the 4 edge slots
    a0 += __shfl_xor(a0, 16); a1 += __shfl_xor(a1, 16);
    a2 += __shfl_xor(a2, 16); a3 += __shfl_xor(a3, 16);
    a0 += __shfl_xor(a0, 32); a1 += __shfl_xor(a1, 32);
    a2 += __shfl_xor(a2, 32); a3 += __shfl_xor(a3, 32);

    if (WOUT || ACC != 0) {
        float dn = dcol_in[(unsigned)n * 4u + f];
        if (l < 16) {
            unsigned oidx = ((unsigned)n << 6) + moff;
            float4 val = make_float4(a0 * dn, a1 * dn, a2 * dn, a3 * dn);
            if (WOUT) *(float4*)(out + oidx) = val;
            if (ACC == 1) {
                float4 c = *(const float4*)(acc + oidx);
                *(float4*)(acc + oidx) =
                    make_float4(c.x + val.x, c.y + val.y, c.z + val.z, c.w + val.w);
            } else if (ACC == 2) {
                const float k3 = 1.0f / 3.0f;
                float4 c = *(const float4*)(acc + oidx);
                *(float4*)(acc + oidx) =
                    make_float4((c.x + val.x) * k3, (c.y + val.y) * k3,
                                (c.z + val.z) * k3, (c.w + val.w) * k3);
            }
        }
    }
    if (!ROUTE) return;

    // head = l2norm per factor (dcol[n] scale-invariant)
    float ss = a0 * a0 + a1 * a1 + a2 * a2 + a3 * a3;
    ss += __shfl_xor(ss, 1);
    ss += __shfl_xor(ss, 2);
    float inv = 1.0f / fmaxf(sqrtf(ss), 1e-12f);
    f32x2 h01 = {a0 * inv, a1 * inv};
    f32x2 h23 = {a2 * inv, a3 * inv};

    float rowsumf = 0.f;

#pragma unroll 2
    for (int k = s; k < e; k += 8) {
        int e1 = k + g, e2 = e1 + 4;
        bool v1 = e1 < e, v2 = e2 < e;
        unsigned c1 = (unsigned)(v1 ? e1 : s);
        unsigned c2 = (unsigned)(v2 ? e2 : s);
        unsigned t1 = (unsigned)csr_t[c1];
        unsigned t2 = (unsigned)csr_t[c2];
        const uint4 w1 = *(const uint4*)(xt + (t1 << 6) + moff);   // L2-hot (loop1 lines)
        const uint4 w2 = *(const uint4*)(xt + (t2 << 6) + moff);
        f32x2 dv1 = h01 * (f32x2){hi16(w1.x), hi16(w1.y)}
                  + h23 * (f32x2){hi16(w1.z), hi16(w1.w)};
        f32x2 dv2 = h01 * (f32x2){hi16(w2.x), hi16(w2.y)}
                  + h23 * (f32x2){hi16(w2.z), hi16(w2.w)};
        float d1 = dv1.x + dv1.y;
        float d2 = dv2.x + dv2.y;
        d1 += __shfl_xor(d1, 1); d1 += __shfl_xor(d1, 2);
        d2 += __shfl_xor(d2, 1); d2 += __shfl_xor(d2, 2);
        unsigned ai1 = c1 * 4u + f;
        unsigned ai2 = c2 * 4u + f;
        float na1 = Acsr[ai1] + d1;
        float na2 = Acsr[ai2] + d2;
        // softmax over the 4 factors (lane bits 2..3 of m), no max-sub: |A|<=13
        float ex1 = __expf(na1);
        float ex2 = __expf(na2);
        float se1 = ex1 + __shfl_xor(ex1, 4); se1 += __shfl_xor(se1, 8);
        float se2 = ex2 + __shfl_xor(ex2, 4); se2 += __shfl_xor(se2, 8);
        float p1 = ex1 * __builtin_amdgcn_rcpf(se1);
        float p2 = ex2 * __builtin_amdgcn_rcpf(se2);
        if ((m & 3) == 0) {
            if (v1) { Acsr[ai1] = na1; prob[ai1] = p1; }
            if (v2) { Acsr[ai2] = na2; prob[ai2] = p2; }
        }
        rowsumf += (v1 ? p1 : 0.f) + (v2 ? p2 : 0.f);
    }

    rowsumf += __shfl_xor(rowsumf, 16);
    rowsumf += __shfl_xor(rowsumf, 32);
    if (l < 16 && (m & 3) == 0) dcol_out[(unsigned)n * 4u + f] = rsqrtf(rowsumf);
}

extern "C" void kernel_launch(void* const* d_in, const int* in_sizes, int n_in,
                              void* d_out, int out_size, void* d_ws, size_t ws_size,
                              hipStream_t stream) {
    const float* user_emb = (const float*)d_in[0];
    const float* item_emb = (const float*)d_in[1];
    const int* h = (const int*)d_in[2];
    const int* t = (const int*)d_in[3];

    const int nu_elems = in_sizes[0];
    const int ni_elems = in_sizes[1];
    const int total = nu_elems + ni_elems;   // N * 64
    const int N = total / DEMB;
    const int E = in_sizes[2];
    const int NB = (N + 255) >> 8;           // buckets (<= 1024)
    const int NBLK = 256;
    const int EPB = (E + NBLK - 1) / NBLK;

    float* acc = (float*)d_out;

    // ---- workspace layout ----
    float* x     = (float*)d_ws;                    // total f32
    float* out   = x + (size_t)total;               // total f32
    float* Acsr  = out + (size_t)total;             // 4E f32
    float* prob  = Acsr + (size_t)4 * E;            // 4E f32 (first E aliased as stg)
    float* dcolA = prob + (size_t)4 * E;            // 4N f32
    float* dcolB = dcolA + (size_t)4 * N;           // 4N f32
    unsigned* xt = (unsigned*)(dcolB + (size_t)4 * N); // total u32 (packed xs|tail)
    int* ghist   = (int*)(xt + (size_t)total);      // NB*256
    int* btot    = ghist + (size_t)NB * 256;        // NB
    int* bbase   = btot + ((NB + 3) & ~3);          // NB+1
    int* off     = bbase + ((NB + 5) & ~3);         // N+1
    int* csr_t   = off + ((N + 4) & ~3);            // E
    unsigned* stg = (unsigned*)prob;                // E (time-disjoint with prob)

    const int BLK = 256;
    const int gE = (E + BLK - 1) / BLK;
    const int gTot = (total + BLK - 1) / BLK;
    const int gN = (N + BLK - 1) / BLK;
    const int gNodeWave = (N * 64 + BLK - 1) / BLK;

    concat_copy_kernel<<<gTot, BLK, 0, stream>>>(user_emb, item_emb, x, acc, nu_elems, total);

    // CSR build (deterministic, no contended global atomics)
    hist_kernel<<<NBLK, 256, 0, stream>>>(h, ghist, E, EPB, NB);
    btot_kernel<<<NB, 256, 0, stream>>>(ghist, btot);
    bscan_kernel<<<1, 1024, 0, stream>>>(btot, bbase, NB, E);
    bofs_kernel<<<NB, 256, 0, stream>>>(ghist, bbase);
    scatter_kernel<<<NBLK, 256, 0, stream>>>(h, t, ghist, stg, E, EPB, NB);
    finalize_kernel<<<NB, 256, 0, stream>>>(stg, bbase, off, csr_t, N, E);

    init_A_kernel<<<gE, BLK, 0, stream>>>((float4*)Acsr, E);
    dcol0_kernel<<<gN, BLK, 0, stream>>>(off, dcolA, N);

    // ---- layer 0 ----
    prep_kernel<<<gTot, BLK, 0, stream>>>(x, xt, total);
    message_kernel<true, false, true, 0><<<gNodeWave, BLK, 0, stream>>>(
        off, csr_t, Acsr, prob, xt, dcolA, dcolB, out, acc, N);
    message_kernel<false, true, true, 1><<<gNodeWave, BLK, 0, stream>>>(
        off, csr_t, Acsr, prob, xt, dcolB, dcolA, out, acc, N);

    // ---- layer 1 ----
    prep_kernel<<<gTot, BLK, 0, stream>>>(out, xt, total);
    message_kernel<false, false, true, 0><<<gNodeWave, BLK, 0, stream>>>(
        off, csr_t, Acsr, prob, xt, dcolA, dcolB, x, acc, N);
    message_kernel<false, false, false, 2><<<gNodeWave, BLK, 0, stream>>>(
        off, csr_t, Acsr, prob, xt, dcolB, dcolA, x, acc, N);
}

// Round 15
// 573.650 us; speedup vs baseline: 1.1602x; 1.1602x over previous
//
#include <hip/hip_runtime.h>
#include <hip/hip_bf16.h>

#define DEMB 64
typedef unsigned short u16;
typedef float f32x2 __attribute__((ext_vector_type(2)));

__device__ __forceinline__ unsigned f2bf(float f) {
    union { float f; unsigned int i; } c; c.f = f;
    unsigned int r = c.i + 0x7FFF + ((c.i >> 16) & 1);
    return r >> 16;
}
__device__ __forceinline__ float lo16(unsigned int w) {
    union { unsigned int i; float f; } c; c.i = w << 16; return c.f;
}
__device__ __forceinline__ float hi16(unsigned int w) {
    union { unsigned int i; float f; } c; c.i = w & 0xFFFF0000u; return c.f;
}

// odd 7th-order minimax tanh on [-1.02, 1.02], abs err <= ~3e-4
__device__ __forceinline__ float ptanh5(float a) {
    float a2 = a * a;
    float t = fmaf(a2, -0.030095f, 0.124066f);
    t = fmaf(a2, t, -0.332377f);
    t = fmaf(a2, t, 1.0f);
    return a * t;
}

__global__ void init_A_kernel(float4* __restrict__ A, int E) {
    int e = blockIdx.x * blockDim.x + threadIdx.x;
    if (e < E) A[e] = make_float4(1.f, 1.f, 1.f, 1.f);
}

__global__ void concat_copy_kernel(const float* __restrict__ u, const float* __restrict__ it,
                                   float* __restrict__ x, float* __restrict__ acc,
                                   int nu_elems, int total) {
    int i = blockIdx.x * blockDim.x + threadIdx.x;
    if (i >= total) return;
    float v = (i < nu_elems) ? u[i] : it[i - nu_elems];
    x[i] = v;
    acc[i] = v;
}

// ============ CSR build: deterministic histogram radix (R9-proven) ============
__global__ void hist_kernel(const int* __restrict__ h, int* __restrict__ ghist,
                            int E, int EPB, int NB) {
    __shared__ int bins[1024];
    int b = blockIdx.x, tid = threadIdx.x;
    for (int j = tid; j < NB; j += 256) bins[j] = 0;
    __syncthreads();
    int s = b * EPB, e = min(s + EPB, E);
    for (int k = s + tid; k < e; k += 256)
        atomicAdd(&bins[((unsigned)h[k]) >> 8], 1);
    __syncthreads();
    for (int j = tid; j < NB; j += 256) ghist[j * gridDim.x + b] = bins[j];
}

__global__ void btot_kernel(const int* __restrict__ ghist, int* __restrict__ btot) {
    __shared__ int s[256];
    int j = blockIdx.x, tid = threadIdx.x;
    s[tid] = ghist[j * 256 + tid];
    __syncthreads();
    for (int o = 128; o >= 1; o >>= 1) {
        if (tid < o) s[tid] += s[tid + o];
        __syncthreads();
    }
    if (tid == 0) btot[j] = s[0];
}

__global__ void bscan_kernel(const int* __restrict__ btot, int* __restrict__ bbase,
                             int NB, int E) {
    __shared__ int s[1024];
    int tid = threadIdx.x;
    int v = (tid < NB) ? btot[tid] : 0;
    s[tid] = v;
    __syncthreads();
    for (int o = 1; o < 1024; o <<= 1) {
        int a = (tid >= o) ? s[tid - o] : 0;
        __syncthreads();
        s[tid] += a;
        __syncthreads();
    }
    if (tid < NB) bbase[tid] = s[tid] - v;
    if (tid == 0) bbase[NB] = E;
}

__global__ void bofs_kernel(int* __restrict__ ghist, const int* __restrict__ bbase) {
    __shared__ int s[256];
    int j = blockIdx.x, tid = threadIdx.x;
    int v = ghist[j * 256 + tid];
    s[tid] = v;
    __syncthreads();
    for (int o = 1; o < 256; o <<= 1) {
        int a = (tid >= o) ? s[tid - o] : 0;
        __syncthreads();
        s[tid] += a;
        __syncthreads();
    }
    ghist[j * 256 + tid] = bbase[j] + s[tid] - v;
}

__global__ void scatter_kernel(const int* __restrict__ h, const int* __restrict__ t,
                               const int* __restrict__ ghist, unsigned* __restrict__ stg,
                               int E, int EPB, int NB) {
    __shared__ int cur[1024];
    int b = blockIdx.x, tid = threadIdx.x;
    for (int j = tid; j < NB; j += 256) cur[j] = ghist[j * gridDim.x + b];
    __syncthreads();
    int s = b * EPB, e = min(s + EPB, E);
    for (int k = s + tid; k < e; k += 256) {
        unsigned hh = (unsigned)h[k];
        int pos = atomicAdd(&cur[hh >> 8], 1);
        stg[pos] = ((hh & 255u) << 18) | (unsigned)t[k];
    }
}

__global__ void finalize_kernel(const unsigned* __restrict__ stg, const int* __restrict__ bbase,
                                int* __restrict__ off, int* __restrict__ csr_t, int N, int E) {
    __shared__ int cnt[256];
    __shared__ int scn[256];
    int b = blockIdx.x, tid = threadIdx.x;
    int ebeg = bbase[b], eend = bbase[b + 1];
    cnt[tid] = 0;
    __syncthreads();
    for (int k = ebeg + tid; k < eend; k += 256)
        atomicAdd(&cnt[(stg[k] >> 18) & 255u], 1);
    __syncthreads();
    int v = cnt[tid];
    scn[tid] = v;
    __syncthreads();
    for (int o = 1; o < 256; o <<= 1) {
        int a = (tid >= o) ? scn[tid - o] : 0;
        __syncthreads();
        scn[tid] += a;
        __syncthreads();
    }
    int excl = scn[tid] - v;
    int gn = (b << 8) + tid;
    if (gn < N) off[gn] = ebeg + excl;
    if (b == 0 && tid == 0) off[N] = E;
    __syncthreads();
    cnt[tid] = excl;   // reuse as cursor
    __syncthreads();
    for (int k = ebeg + tid; k < eend; k += 256) {
        unsigned en = stg[k];
        int slot = atomicAdd(&cnt[(en >> 18) & 255u], 1);
        csr_t[ebeg + slot] = (int)(en & 0x3FFFFu);
    }
}

// bootstrap: prob=0.25 folded -> dcol0 = 0.5/sqrt(deg)
__global__ void dcol0_kernel(const int* __restrict__ off, float* __restrict__ dcol, int N) {
    int n = blockIdx.x * blockDim.x + threadIdx.x;
    if (n >= N) return;
    float v = 0.5f * rsqrtf((float)(off[n + 1] - off[n]));
    *(float4*)(dcol + (size_t)n * 4) = make_float4(v, v, v, v);
}

// ============ per-layer: xs = bf16(x); tailt = bf16(tanh(x/||x_f||))
__global__ void prep_kernel(const float* __restrict__ x, u16* __restrict__ xs,
                            u16* __restrict__ tailt, int total) {
    int i = blockIdx.x * blockDim.x + threadIdx.x;
    if (i >= total) return;
    float v = x[i];
    xs[i] = (u16)f2bf(v);
    float s = v * v;
#pragma unroll
    for (int o = 8; o >= 1; o >>= 1) s += __shfl_xor(s, o);
    float nr = fmaxf(sqrtf(s), 1e-12f);
    tailt[i] = (u16)f2bf(ptanh5(v * __builtin_amdgcn_rcpf(nr)));
}

// ============ fused message + routing + next-iteration softmax/dcol
// One 64-lane wave per node. lane l: g=l>>3 (EIGHT edge slots), m=l&7 (col
// octet: cols 8m..8m+7 via one uint4 = 8 bf16), f=m>>1. One wave-gather
// serves 8 edges -> half the loads/index math of the 4-slot layout.
// ACC: 0=none, 1=acc+=val, 2=acc=(acc+val)/3 (final mean)
template <bool UNI, bool WOUT, bool ROUTE, int ACC>
__global__ void message_kernel(const int* __restrict__ off, const int* __restrict__ csr_t,
                               float* __restrict__ Acsr, float* __restrict__ prob,
                               const u16* __restrict__ xs, const u16* __restrict__ tailt,
                               const float* __restrict__ dcol_in, float* __restrict__ dcol_out,
                               float* __restrict__ out, float* __restrict__ acc, int N) {
    int gid = blockIdx.x * blockDim.x + threadIdx.x;
    int n = gid >> 6;
    if (n >= N) return;
    int l = gid & 63;
    int g = l >> 3;
    int m = l & 7;
    unsigned f = (unsigned)(m >> 1);
    int s = off[n], e = off[n + 1];
    unsigned moff = (unsigned)(m << 3);   // u16 index within the 64-wide row

    f32x2 a01 = {0.f, 0.f}, a23 = {0.f, 0.f}, a45 = {0.f, 0.f}, a67 = {0.f, 0.f};

#pragma unroll 2
    for (int k = s; k < e; k += 16) {
        int e1 = k + g, e2 = e1 + 8;
        bool v1 = e1 < e, v2 = e2 < e;
        unsigned c1 = (unsigned)(v1 ? e1 : s);
        unsigned c2 = (unsigned)(v2 ? e2 : s);
        unsigned t1 = (unsigned)csr_t[c1];
        unsigned t2 = (unsigned)csr_t[c2];
        float p1, p2;
        if (UNI) {
            p1 = dcol_in[t1 * 4u + f];
            p2 = dcol_in[t2 * 4u + f];
        } else {
            p1 = prob[c1 * 4u + f] * dcol_in[t1 * 4u + f];
            p2 = prob[c2 * 4u + f] * dcol_in[t2 * 4u + f];
        }
        p1 = v1 ? p1 : 0.f;
        p2 = v2 ? p2 : 0.f;
        const uint4 w1 = *(const uint4*)(xs + (t1 << 6) + moff);
        const uint4 w2 = *(const uint4*)(xs + (t2 << 6) + moff);
        a01 += p1 * (f32x2){lo16(w1.x), hi16(w1.x)} + p2 * (f32x2){lo16(w2.x), hi16(w2.x)};
        a23 += p1 * (f32x2){lo16(w1.y), hi16(w1.y)} + p2 * (f32x2){lo16(w2.y), hi16(w2.y)};
        a45 += p1 * (f32x2){lo16(w1.z), hi16(w1.z)} + p2 * (f32x2){lo16(w2.z), hi16(w2.z)};
        a67 += p1 * (f32x2){lo16(w1.w), hi16(w1.w)} + p2 * (f32x2){lo16(w2.w), hi16(w2.w)};
    }

    float a0 = a01.x, a1 = a01.y, a2 = a23.x, a3 = a23.y;
    float a4 = a45.x, a5 = a45.y, a6 = a67.x, a7 = a67.y;
    // combine the 8 edge slots -> every lane holds full sums for its 8 cols
#pragma unroll
    for (int o = 8; o <= 32; o <<= 1) {
        a0 += __shfl_xor(a0, o); a1 += __shfl_xor(a1, o);
        a2 += __shfl_xor(a2, o); a3 += __shfl_xor(a3, o);
        a4 += __shfl_xor(a4, o); a5 += __shfl_xor(a5, o);
        a6 += __shfl_xor(a6, o); a7 += __shfl_xor(a7, o);
    }

    if (WOUT || ACC != 0) {
        float dn = dcol_in[(unsigned)n * 4u + f];
        if (l < 8) {
            unsigned oidx = ((unsigned)n << 6) + moff;
            float4 lo = make_float4(a0 * dn, a1 * dn, a2 * dn, a3 * dn);
            float4 hi = make_float4(a4 * dn, a5 * dn, a6 * dn, a7 * dn);
            if (WOUT) {
                *(float4*)(out + oidx) = lo;
                *(float4*)(out + oidx + 4) = hi;
            }
            if (ACC == 1) {
                float4 c0 = *(const float4*)(acc + oidx);
                float4 c1 = *(const float4*)(acc + oidx + 4);
                *(float4*)(acc + oidx) =
                    make_float4(c0.x + lo.x, c0.y + lo.y, c0.z + lo.z, c0.w + lo.w);
                *(float4*)(acc + oidx + 4) =
                    make_float4(c1.x + hi.x, c1.y + hi.y, c1.z + hi.z, c1.w + hi.w);
            } else if (ACC == 2) {
                const float k3 = 1.0f / 3.0f;
                float4 c0 = *(const float4*)(acc + oidx);
                float4 c1 = *(const float4*)(acc + oidx + 4);
                *(float4*)(acc + oidx) =
                    make_float4((c0.x + lo.x) * k3, (c0.y + lo.y) * k3,
                                (c0.z + lo.z) * k3, (c0.w + lo.w) * k3);
                *(float4*)(acc + oidx + 4) =
                    make_float4((c1.x + hi.x) * k3, (c1.y + hi.y) * k3,
                                (c1.z + hi.z) * k3, (c1.w + hi.w) * k3);
            }
        }
    }
    if (!ROUTE) return;

    // head = l2norm per factor (dcol[n] scale-invariant); 16 cols = this lane's
    // 8 + partner lane's 8 (xor 1)
    float ss = a0 * a0 + a1 * a1 + a2 * a2 + a3 * a3
             + a4 * a4 + a5 * a5 + a6 * a6 + a7 * a7;
    ss += __shfl_xor(ss, 1);
    float inv = 1.0f / fmaxf(sqrtf(ss), 1e-12f);
    f32x2 h01 = {a0 * inv, a1 * inv};
    f32x2 h23 = {a2 * inv, a3 * inv};
    f32x2 h45 = {a4 * inv, a5 * inv};
    f32x2 h67 = {a6 * inv, a7 * inv};

    float rowsumf = 0.f;

#pragma unroll 2
    for (int k = s; k < e; k += 16) {
        int e1 = k + g, e2 = e1 + 8;
        bool v1 = e1 < e, v2 = e2 < e;
        unsigned c1 = (unsigned)(v1 ? e1 : s);
        unsigned c2 = (unsigned)(v2 ? e2 : s);
        unsigned t1 = (unsigned)csr_t[c1];
        unsigned t2 = (unsigned)csr_t[c2];
        const uint4 u1 = *(const uint4*)(tailt + (t1 << 6) + moff);
        const uint4 u2 = *(const uint4*)(tailt + (t2 << 6) + moff);
        f32x2 dv1 = h01 * (f32x2){lo16(u1.x), hi16(u1.x)}
                  + h23 * (f32x2){lo16(u1.y), hi16(u1.y)}
                  + h45 * (f32x2){lo16(u1.z), hi16(u1.z)}
                  + h67 * (f32x2){lo16(u1.w), hi16(u1.w)};
        f32x2 dv2 = h01 * (f32x2){lo16(u2.x), hi16(u2.x)}
                  + h23 * (f32x2){lo16(u2.y), hi16(u2.y)}
                  + h45 * (f32x2){lo16(u2.z), hi16(u2.z)}
                  + h67 * (f32x2){lo16(u2.w), hi16(u2.w)};
        float d1 = dv1.x + dv1.y;
        float d2 = dv2.x + dv2.y;
        d1 += __shfl_xor(d1, 1);   // partner lane completes the 16-col dot
        d2 += __shfl_xor(d2, 1);
        unsigned ai1 = c1 * 4u + f;
        unsigned ai2 = c2 * 4u + f;
        float na1 = Acsr[ai1] + d1;
        float na2 = Acsr[ai2] + d2;
        // softmax over the 4 factors (xor 2: f0<->f1, f2<->f3; xor 4: pairs)
        float ex1 = __expf(na1);
        float ex2 = __expf(na2);
        float se1 = ex1 + __shfl_xor(ex1, 2); se1 += __shfl_xor(se1, 4);
        float se2 = ex2 + __shfl_xor(ex2, 2); se2 += __shfl_xor(se2, 4);
        float p1 = ex1 * __builtin_amdgcn_rcpf(se1);
        float p2 = ex2 * __builtin_amdgcn_rcpf(se2);
        if ((m & 1) == 0) {
            if (v1) { Acsr[ai1] = na1; prob[ai1] = p1; }
            if (v2) { Acsr[ai2] = na2; prob[ai2] = p2; }
        }
        rowsumf += (v1 ? p1 : 0.f) + (v2 ? p2 : 0.f);
    }

    // sum over the 8 slots
    rowsumf += __shfl_xor(rowsumf, 8);
    rowsumf += __shfl_xor(rowsumf, 16);
    rowsumf += __shfl_xor(rowsumf, 32);
    if (l < 8 && (m & 1) == 0) dcol_out[(unsigned)n * 4u + f] = rsqrtf(rowsumf);
}

extern "C" void kernel_launch(void* const* d_in, const int* in_sizes, int n_in,
                              void* d_out, int out_size, void* d_ws, size_t ws_size,
                              hipStream_t stream) {
    const float* user_emb = (const float*)d_in[0];
    const float* item_emb = (const float*)d_in[1];
    const int* h = (const int*)d_in[2];
    const int* t = (const int*)d_in[3];

    const int nu_elems = in_sizes[0];
    const int ni_elems = in_sizes[1];
    const int total = nu_elems + ni_elems;   // N * 64
    const int N = total / DEMB;
    const int E = in_sizes[2];
    const int NB = (N + 255) >> 8;           // buckets (<= 1024)
    const int NBLK = 256;
    const int EPB = (E + NBLK - 1) / NBLK;

    float* acc = (float*)d_out;

    // ---- workspace layout (R12) ----
    float* x     = (float*)d_ws;                    // total f32
    float* out   = x + (size_t)total;               // total f32
    float* Acsr  = out + (size_t)total;             // 4E f32
    float* prob  = Acsr + (size_t)4 * E;            // 4E f32 (first E aliased as stg)
    float* dcolA = prob + (size_t)4 * E;            // 4N f32
    float* dcolB = dcolA + (size_t)4 * N;           // 4N f32
    u16* xs      = (u16*)(dcolB + (size_t)4 * N);   // total u16
    u16* tailt   = xs + (size_t)total;              // total u16
    int* ghist   = (int*)(tailt + (size_t)total);   // NB*256
    int* btot    = ghist + (size_t)NB * 256;        // NB
    int* bbase   = btot + ((NB + 3) & ~3);          // NB+1
    int* off     = bbase + ((NB + 5) & ~3);         // N+1
    int* csr_t   = off + ((N + 4) & ~3);            // E
    unsigned* stg = (unsigned*)prob;                // E (time-disjoint with prob)

    const int BLK = 256;
    const int gE = (E + BLK - 1) / BLK;
    const int gTot = (total + BLK - 1) / BLK;
    const int gN = (N + BLK - 1) / BLK;
    const int gNodeWave = (N * 64 + BLK - 1) / BLK;

    concat_copy_kernel<<<gTot, BLK, 0, stream>>>(user_emb, item_emb, x, acc, nu_elems, total);

    // CSR build (deterministic, no contended global atomics)
    hist_kernel<<<NBLK, 256, 0, stream>>>(h, ghist, E, EPB, NB);
    btot_kernel<<<NB, 256, 0, stream>>>(ghist, btot);
    bscan_kernel<<<1, 1024, 0, stream>>>(btot, bbase, NB, E);
    bofs_kernel<<<NB, 256, 0, stream>>>(ghist, bbase);
    scatter_kernel<<<NBLK, 256, 0, stream>>>(h, t, ghist, stg, E, EPB, NB);
    finalize_kernel<<<NB, 256, 0, stream>>>(stg, bbase, off, csr_t, N, E);

    init_A_kernel<<<gE, BLK, 0, stream>>>((float4*)Acsr, E);
    dcol0_kernel<<<gN, BLK, 0, stream>>>(off, dcolA, N);

    // ---- layer 0 ----
    prep_kernel<<<gTot, BLK, 0, stream>>>(x, xs, tailt, total);
    message_kernel<true, false, true, 0><<<gNodeWave, BLK, 0, stream>>>(
        off, csr_t, Acsr, prob, xs, tailt, dcolA, dcolB, out, acc, N);
    message_kernel<false, true, true, 1><<<gNodeWave, BLK, 0, stream>>>(
        off, csr_t, Acsr, prob, xs, tailt, dcolB, dcolA, out, acc, N);

    // ---- layer 1 ----
    prep_kernel<<<gTot, BLK, 0, stream>>>(out, xs, tailt, total);
    message_kernel<false, false, true, 0><<<gNodeWave, BLK, 0, stream>>>(
        off, csr_t, Acsr, prob, xs, tailt, dcolA, dcolB, x, acc, N);
    message_kernel<false, false, false, 2><<<gNodeWave, BLK, 0, stream>>>(
        off, csr_t, Acsr, prob, xs, tailt, dcolB, dcolA, x, acc, N);
}

// Round 16
// 573.461 us; speedup vs baseline: 1.1605x; 1.0003x over previous
//
#include <hip/hip_runtime.h>
#include <hip/hip_bf16.h>

#define DEMB 64
typedef unsigned short u16;
typedef _Float16 f16;
typedef _Float16 f16x2 __attribute__((ext_vector_type(2)));
typedef float f32x2 __attribute__((ext_vector_type(2)));

#if defined(__has_builtin)
#if __has_builtin(__builtin_amdgcn_fdot2)
#define USE_FDOT2 1
#endif
#endif

__device__ __forceinline__ u16 f2h(float f) {
    union { f16 h; u16 u; } c; c.h = (f16)f; return c.u;
}

// odd 7th-order minimax tanh on [-1.02, 1.02], abs err <= ~3e-4
__device__ __forceinline__ float ptanh5(float a) {
    float a2 = a * a;
    float t = fmaf(a2, -0.030095f, 0.124066f);
    t = fmaf(a2, t, -0.332377f);
    t = fmaf(a2, t, 1.0f);
    return a * t;
}

__global__ void init_A_kernel(float4* __restrict__ A, int E) {
    int e = blockIdx.x * blockDim.x + threadIdx.x;
    if (e < E) A[e] = make_float4(1.f, 1.f, 1.f, 1.f);
}

__global__ void concat_copy_kernel(const float* __restrict__ u, const float* __restrict__ it,
                                   float* __restrict__ x, float* __restrict__ acc,
                                   int nu_elems, int total) {
    int i = blockIdx.x * blockDim.x + threadIdx.x;
    if (i >= total) return;
    float v = (i < nu_elems) ? u[i] : it[i - nu_elems];
    x[i] = v;
    acc[i] = v;
}

// ============ CSR build: deterministic histogram radix (R9-proven) ============
__global__ void hist_kernel(const int* __restrict__ h, int* __restrict__ ghist,
                            int E, int EPB, int NB) {
    __shared__ int bins[1024];
    int b = blockIdx.x, tid = threadIdx.x;
    for (int j = tid; j < NB; j += 256) bins[j] = 0;
    __syncthreads();
    int s = b * EPB, e = min(s + EPB, E);
    for (int k = s + tid; k < e; k += 256)
        atomicAdd(&bins[((unsigned)h[k]) >> 8], 1);
    __syncthreads();
    for (int j = tid; j < NB; j += 256) ghist[j * gridDim.x + b] = bins[j];
}

__global__ void btot_kernel(const int* __restrict__ ghist, int* __restrict__ btot) {
    __shared__ int s[256];
    int j = blockIdx.x, tid = threadIdx.x;
    s[tid] = ghist[j * 256 + tid];
    __syncthreads();
    for (int o = 128; o >= 1; o >>= 1) {
        if (tid < o) s[tid] += s[tid + o];
        __syncthreads();
    }
    if (tid == 0) btot[j] = s[0];
}

__global__ void bscan_kernel(const int* __restrict__ btot, int* __restrict__ bbase,
                             int NB, int E) {
    __shared__ int s[1024];
    int tid = threadIdx.x;
    int v = (tid < NB) ? btot[tid] : 0;
    s[tid] = v;
    __syncthreads();
    for (int o = 1; o < 1024; o <<= 1) {
        int a = (tid >= o) ? s[tid - o] : 0;
        __syncthreads();
        s[tid] += a;
        __syncthreads();
    }
    if (tid < NB) bbase[tid] = s[tid] - v;
    if (tid == 0) bbase[NB] = E;
}

__global__ void bofs_kernel(int* __restrict__ ghist, const int* __restrict__ bbase) {
    __shared__ int s[256];
    int j = blockIdx.x, tid = threadIdx.x;
    int v = ghist[j * 256 + tid];
    s[tid] = v;
    __syncthreads();
    for (int o = 1; o < 256; o <<= 1) {
        int a = (tid >= o) ? s[tid - o] : 0;
        __syncthreads();
        s[tid] += a;
        __syncthreads();
    }
    ghist[j * 256 + tid] = bbase[j] + s[tid] - v;
}

__global__ void scatter_kernel(const int* __restrict__ h, const int* __restrict__ t,
                               const int* __restrict__ ghist, unsigned* __restrict__ stg,
                               int E, int EPB, int NB) {
    __shared__ int cur[1024];
    int b = blockIdx.x, tid = threadIdx.x;
    for (int j = tid; j < NB; j += 256) cur[j] = ghist[j * gridDim.x + b];
    __syncthreads();
    int s = b * EPB, e = min(s + EPB, E);
    for (int k = s + tid; k < e; k += 256) {
        unsigned hh = (unsigned)h[k];
        int pos = atomicAdd(&cur[hh >> 8], 1);
        stg[pos] = ((hh & 255u) << 18) | (unsigned)t[k];
    }
}

__global__ void finalize_kernel(const unsigned* __restrict__ stg, const int* __restrict__ bbase,
                                int* __restrict__ off, int* __restrict__ csr_t, int N, int E) {
    __shared__ int cnt[256];
    __shared__ int scn[256];
    int b = blockIdx.x, tid = threadIdx.x;
    int ebeg = bbase[b], eend = bbase[b + 1];
    cnt[tid] = 0;
    __syncthreads();
    for (int k = ebeg + tid; k < eend; k += 256)
        atomicAdd(&cnt[(stg[k] >> 18) & 255u], 1);
    __syncthreads();
    int v = cnt[tid];
    scn[tid] = v;
    __syncthreads();
    for (int o = 1; o < 256; o <<= 1) {
        int a = (tid >= o) ? scn[tid - o] : 0;
        __syncthreads();
        scn[tid] += a;
        __syncthreads();
    }
    int excl = scn[tid] - v;
    int gn = (b << 8) + tid;
    if (gn < N) off[gn] = ebeg + excl;
    if (b == 0 && tid == 0) off[N] = E;
    __syncthreads();
    cnt[tid] = excl;   // reuse as cursor
    __syncthreads();
    for (int k = ebeg + tid; k < eend; k += 256) {
        unsigned en = stg[k];
        int slot = atomicAdd(&cnt[(en >> 18) & 255u], 1);
        csr_t[ebeg + slot] = (int)(en & 0x3FFFFu);
    }
}

// bootstrap: prob=0.25 folded -> dcol0 = 0.5/sqrt(deg)
__global__ void dcol0_kernel(const int* __restrict__ off, float* __restrict__ dcol, int N) {
    int n = blockIdx.x * blockDim.x + threadIdx.x;
    if (n >= N) return;
    float v = 0.5f * rsqrtf((float)(off[n + 1] - off[n]));
    *(float4*)(dcol + (size_t)n * 4) = make_float4(v, v, v, v);
}

// ============ per-layer: xs = f16(x); tailt = f16(tanh(x/||x_f||))
__global__ void prep_kernel(const float* __restrict__ x, u16* __restrict__ xs,
                            u16* __restrict__ tailt, int total) {
    int i = blockIdx.x * blockDim.x + threadIdx.x;
    if (i >= total) return;
    float v = x[i];
    xs[i] = f2h(v);
    float s = v * v;
#pragma unroll
    for (int o = 8; o >= 1; o >>= 1) s += __shfl_xor(s, o);
    float nr = fmaxf(sqrtf(s), 1e-12f);
    tailt[i] = f2h(ptanh5(v * __builtin_amdgcn_rcpf(nr)));
}

// ============ fused message + routing + next-iteration softmax/dcol
// One 64-lane wave per node. lane l: g=l>>3 (8 edge slots), m=l&7 (col octet,
// one uint4 = 8 f16), f=m>>1. Tables in f16 -> loop1 uses v_fma_mix
// (conversion folded into FMA), loop2 uses v_dot2_f32_f16 where available.
// ACC: 0=none, 1=acc+=val, 2=acc=(acc+val)/3 (final mean)
template <bool UNI, bool WOUT, bool ROUTE, int ACC>
__global__ void message_kernel(const int* __restrict__ off, const int* __restrict__ csr_t,
                               float* __restrict__ Acsr, float* __restrict__ prob,
                               const u16* __restrict__ xs, const u16* __restrict__ tailt,
                               const float* __restrict__ dcol_in, float* __restrict__ dcol_out,
                               float* __restrict__ out, float* __restrict__ acc, int N) {
    int gid = blockIdx.x * blockDim.x + threadIdx.x;
    int n = gid >> 6;
    if (n >= N) return;
    int l = gid & 63;
    int g = l >> 3;
    int m = l & 7;
    unsigned f = (unsigned)(m >> 1);
    int s = off[n], e = off[n + 1];
    unsigned moff = (unsigned)(m << 3);   // u16 index within the 64-wide row

    union U8 { uint4 u; f16 h[8]; f16x2 p[4]; };

    float a0 = 0.f, a1 = 0.f, a2 = 0.f, a3 = 0.f;
    float a4 = 0.f, a5 = 0.f, a6 = 0.f, a7 = 0.f;

#pragma unroll 2
    for (int k = s; k < e; k += 16) {
        int e1 = k + g, e2 = e1 + 8;
        bool v1 = e1 < e, v2 = e2 < e;
        unsigned c1 = (unsigned)(v1 ? e1 : s);
        unsigned c2 = (unsigned)(v2 ? e2 : s);
        unsigned t1 = (unsigned)csr_t[c1];
        unsigned t2 = (unsigned)csr_t[c2];
        float p1, p2;
        if (UNI) {
            p1 = dcol_in[t1 * 4u + f];
            p2 = dcol_in[t2 * 4u + f];
        } else {
            p1 = prob[c1 * 4u + f] * dcol_in[t1 * 4u + f];
            p2 = prob[c2 * 4u + f] * dcol_in[t2 * 4u + f];
        }
        p1 = v1 ? p1 : 0.f;
        p2 = v2 ? p2 : 0.f;
        U8 w1, w2;
        w1.u = *(const uint4*)(xs + (t1 << 6) + moff);
        w2.u = *(const uint4*)(xs + (t2 << 6) + moff);
        // v_fma_mix_f32: f16->f32 conversion folded into the FMA
        a0 = fmaf(p1, (float)w1.h[0], a0); a1 = fmaf(p1, (float)w1.h[1], a1);
        a2 = fmaf(p1, (float)w1.h[2], a2); a3 = fmaf(p1, (float)w1.h[3], a3);
        a4 = fmaf(p1, (float)w1.h[4], a4); a5 = fmaf(p1, (float)w1.h[5], a5);
        a6 = fmaf(p1, (float)w1.h[6], a6); a7 = fmaf(p1, (float)w1.h[7], a7);
        a0 = fmaf(p2, (float)w2.h[0], a0); a1 = fmaf(p2, (float)w2.h[1], a1);
        a2 = fmaf(p2, (float)w2.h[2], a2); a3 = fmaf(p2, (float)w2.h[3], a3);
        a4 = fmaf(p2, (float)w2.h[4], a4); a5 = fmaf(p2, (float)w2.h[5], a5);
        a6 = fmaf(p2, (float)w2.h[6], a6); a7 = fmaf(p2, (float)w2.h[7], a7);
    }

    // combine the 8 edge slots -> every lane holds full sums for its 8 cols
#pragma unroll
    for (int o = 8; o <= 32; o <<= 1) {
        a0 += __shfl_xor(a0, o); a1 += __shfl_xor(a1, o);
        a2 += __shfl_xor(a2, o); a3 += __shfl_xor(a3, o);
        a4 += __shfl_xor(a4, o); a5 += __shfl_xor(a5, o);
        a6 += __shfl_xor(a6, o); a7 += __shfl_xor(a7, o);
    }

    if (WOUT || ACC != 0) {
        float dn = dcol_in[(unsigned)n * 4u + f];
        if (l < 8) {
            unsigned oidx = ((unsigned)n << 6) + moff;
            float4 lo = make_float4(a0 * dn, a1 * dn, a2 * dn, a3 * dn);
            float4 hi = make_float4(a4 * dn, a5 * dn, a6 * dn, a7 * dn);
            if (WOUT) {
                *(float4*)(out + oidx) = lo;
                *(float4*)(out + oidx + 4) = hi;
            }
            if (ACC == 1) {
                float4 c0 = *(const float4*)(acc + oidx);
                float4 c1 = *(const float4*)(acc + oidx + 4);
                *(float4*)(acc + oidx) =
                    make_float4(c0.x + lo.x, c0.y + lo.y, c0.z + lo.z, c0.w + lo.w);
                *(float4*)(acc + oidx + 4) =
                    make_float4(c1.x + hi.x, c1.y + hi.y, c1.z + hi.z, c1.w + hi.w);
            } else if (ACC == 2) {
                const float k3 = 1.0f / 3.0f;
                float4 c0 = *(const float4*)(acc + oidx);
                float4 c1 = *(const float4*)(acc + oidx + 4);
                *(float4*)(acc + oidx) =
                    make_float4((c0.x + lo.x) * k3, (c0.y + lo.y) * k3,
                                (c0.z + lo.z) * k3, (c0.w + lo.w) * k3);
                *(float4*)(acc + oidx + 4) =
                    make_float4((c1.x + hi.x) * k3, (c1.y + hi.y) * k3,
                                (c1.z + hi.z) * k3, (c1.w + hi.w) * k3);
            }
        }
    }
    if (!ROUTE) return;

    // head = l2norm per factor (dcol[n] scale-invariant); 16 cols = this lane's
    // 8 + partner lane's 8 (xor 1)
    float ss = a0 * a0 + a1 * a1 + a2 * a2 + a3 * a3
             + a4 * a4 + a5 * a5 + a6 * a6 + a7 * a7;
    ss += __shfl_xor(ss, 1);
    float inv = 1.0f / fmaxf(sqrtf(ss), 1e-12f);
    float h0 = a0 * inv, h1 = a1 * inv, h2 = a2 * inv, h3 = a3 * inv;
    float h4 = a4 * inv, h5 = a5 * inv, h6 = a6 * inv, h7 = a7 * inv;
#ifdef USE_FDOT2
    f16x2 hp0 = {(f16)h0, (f16)h1};
    f16x2 hp1 = {(f16)h2, (f16)h3};
    f16x2 hp2 = {(f16)h4, (f16)h5};
    f16x2 hp3 = {(f16)h6, (f16)h7};
#endif

    float rowsumf = 0.f;

#pragma unroll 2
    for (int k = s; k < e; k += 16) {
        int e1 = k + g, e2 = e1 + 8;
        bool v1 = e1 < e, v2 = e2 < e;
        unsigned c1 = (unsigned)(v1 ? e1 : s);
        unsigned c2 = (unsigned)(v2 ? e2 : s);
        unsigned t1 = (unsigned)csr_t[c1];
        unsigned t2 = (unsigned)csr_t[c2];
        U8 u1, u2;
        u1.u = *(const uint4*)(tailt + (t1 << 6) + moff);
        u2.u = *(const uint4*)(tailt + (t2 << 6) + moff);
        float d1, d2;
#ifdef USE_FDOT2
        d1 = __builtin_amdgcn_fdot2(hp0, u1.p[0], 0.f, false);
        d1 = __builtin_amdgcn_fdot2(hp1, u1.p[1], d1, false);
        d1 = __builtin_amdgcn_fdot2(hp2, u1.p[2], d1, false);
        d1 = __builtin_amdgcn_fdot2(hp3, u1.p[3], d1, false);
        d2 = __builtin_amdgcn_fdot2(hp0, u2.p[0], 0.f, false);
        d2 = __builtin_amdgcn_fdot2(hp1, u2.p[1], d2, false);
        d2 = __builtin_amdgcn_fdot2(hp2, u2.p[2], d2, false);
        d2 = __builtin_amdgcn_fdot2(hp3, u2.p[3], d2, false);
#else
        d1 = h0 * (float)u1.h[0] + h1 * (float)u1.h[1]
           + h2 * (float)u1.h[2] + h3 * (float)u1.h[3]
           + h4 * (float)u1.h[4] + h5 * (float)u1.h[5]
           + h6 * (float)u1.h[6] + h7 * (float)u1.h[7];
        d2 = h0 * (float)u2.h[0] + h1 * (float)u2.h[1]
           + h2 * (float)u2.h[2] + h3 * (float)u2.h[3]
           + h4 * (float)u2.h[4] + h5 * (float)u2.h[5]
           + h6 * (float)u2.h[6] + h7 * (float)u2.h[7];
#endif
        d1 += __shfl_xor(d1, 1);   // partner lane completes the 16-col dot
        d2 += __shfl_xor(d2, 1);
        unsigned ai1 = c1 * 4u + f;
        unsigned ai2 = c2 * 4u + f;
        float na1 = Acsr[ai1] + d1;
        float na2 = Acsr[ai2] + d2;
        // softmax over the 4 factors (xor 2 then xor 4 across f lanes)
        float ex1 = __expf(na1);
        float ex2 = __expf(na2);
        float se1 = ex1 + __shfl_xor(ex1, 2); se1 += __shfl_xor(se1, 4);
        float se2 = ex2 + __shfl_xor(ex2, 2); se2 += __shfl_xor(se2, 4);
        float p1 = ex1 * __builtin_amdgcn_rcpf(se1);
        float p2 = ex2 * __builtin_amdgcn_rcpf(se2);
        if ((m & 1) == 0) {
            if (v1) { Acsr[ai1] = na1; prob[ai1] = p1; }
            if (v2) { Acsr[ai2] = na2; prob[ai2] = p2; }
        }
        rowsumf += (v1 ? p1 : 0.f) + (v2 ? p2 : 0.f);
    }

    // sum over the 8 slots
    rowsumf += __shfl_xor(rowsumf, 8);
    rowsumf += __shfl_xor(rowsumf, 16);
    rowsumf += __shfl_xor(rowsumf, 32);
    if (l < 8 && (m & 1) == 0) dcol_out[(unsigned)n * 4u + f] = rsqrtf(rowsumf);
}

extern "C" void kernel_launch(void* const* d_in, const int* in_sizes, int n_in,
                              void* d_out, int out_size, void* d_ws, size_t ws_size,
                              hipStream_t stream) {
    const float* user_emb = (const float*)d_in[0];
    const float* item_emb = (const float*)d_in[1];
    const int* h = (const int*)d_in[2];
    const int* t = (const int*)d_in[3];

    const int nu_elems = in_sizes[0];
    const int ni_elems = in_sizes[1];
    const int total = nu_elems + ni_elems;   // N * 64
    const int N = total / DEMB;
    const int E = in_sizes[2];
    const int NB = (N + 255) >> 8;           // buckets (<= 1024)
    const int NBLK = 256;
    const int EPB = (E + NBLK - 1) / NBLK;

    float* acc = (float*)d_out;

    // ---- workspace layout (R12/R15) ----
    float* x     = (float*)d_ws;                    // total f32
    float* out   = x + (size_t)total;               // total f32
    float* Acsr  = out + (size_t)total;             // 4E f32
    float* prob  = Acsr + (size_t)4 * E;            // 4E f32 (first E aliased as stg)
    float* dcolA = prob + (size_t)4 * E;            // 4N f32
    float* dcolB = dcolA + (size_t)4 * N;           // 4N f32
    u16* xs      = (u16*)(dcolB + (size_t)4 * N);   // total u16 (f16 bits)
    u16* tailt   = xs + (size_t)total;              // total u16 (f16 bits)
    int* ghist   = (int*)(tailt + (size_t)total);   // NB*256
    int* btot    = ghist + (size_t)NB * 256;        // NB
    int* bbase   = btot + ((NB + 3) & ~3);          // NB+1
    int* off     = bbase + ((NB + 5) & ~3);         // N+1
    int* csr_t   = off + ((N + 4) & ~3);            // E
    unsigned* stg = (unsigned*)prob;                // E (time-disjoint with prob)

    const int BLK = 256;
    const int gE = (E + BLK - 1) / BLK;
    const int gTot = (total + BLK - 1) / BLK;
    const int gN = (N + BLK - 1) / BLK;
    const int gNodeWave = (N * 64 + BLK - 1) / BLK;

    concat_copy_kernel<<<gTot, BLK, 0, stream>>>(user_emb, item_emb, x, acc, nu_elems, total);

    // CSR build (deterministic, no contended global atomics)
    hist_kernel<<<NBLK, 256, 0, stream>>>(h, ghist, E, EPB, NB);
    btot_kernel<<<NB, 256, 0, stream>>>(ghist, btot);
    bscan_kernel<<<1, 1024, 0, stream>>>(btot, bbase, NB, E);
    bofs_kernel<<<NB, 256, 0, stream>>>(ghist, bbase);
    scatter_kernel<<<NBLK, 256, 0, stream>>>(h, t, ghist, stg, E, EPB, NB);
    finalize_kernel<<<NB, 256, 0, stream>>>(stg, bbase, off, csr_t, N, E);

    init_A_kernel<<<gE, BLK, 0, stream>>>((float4*)Acsr, E);
    dcol0_kernel<<<gN, BLK, 0, stream>>>(off, dcolA, N);

    // ---- layer 0 ----
    prep_kernel<<<gTot, BLK, 0, stream>>>(x, xs, tailt, total);
    message_kernel<true, false, true, 0><<<gNodeWave, BLK, 0, stream>>>(
        off, csr_t, Acsr, prob, xs, tailt, dcolA, dcolB, out, acc, N);
    message_kernel<false, true, true, 1><<<gNodeWave, BLK, 0, stream>>>(
        off, csr_t, Acsr, prob, xs, tailt, dcolB, dcolA, out, acc, N);

    // ---- layer 1 ----
    prep_kernel<<<gTot, BLK, 0, stream>>>(out, xs, tailt, total);
    message_kernel<false, false, true, 0><<<gNodeWave, BLK, 0, stream>>>(
        off, csr_t, Acsr, prob, xs, tailt, dcolA, dcolB, x, acc, N);
    message_kernel<false, false, false, 2><<<gNodeWave, BLK, 0, stream>>>(
        off, csr_t, Acsr, prob, xs, tailt, dcolB, dcolA, x, acc, N);
}

// Round 17
// 547.471 us; speedup vs baseline: 1.2156x; 1.0475x over previous
//
#include <hip/hip_runtime.h>
#include <hip/hip_bf16.h>

#define DEMB 64
typedef unsigned short u16;
typedef _Float16 f16;

__device__ __forceinline__ u16 f2h(float f) {
    union { f16 h; u16 u; } c; c.h = (f16)f; return c.u;
}

// odd 7th-order minimax tanh on [-1.02, 1.02], abs err <= ~3e-4
__device__ __forceinline__ float ptanh5(float a) {
    float a2 = a * a;
    float t = fmaf(a2, -0.030095f, 0.124066f);
    t = fmaf(a2, t, -0.332377f);
    t = fmaf(a2, t, 1.0f);
    return a * t;
}

__global__ void init_A_kernel(float4* __restrict__ A, int E) {
    int e = blockIdx.x * blockDim.x + threadIdx.x;
    if (e < E) A[e] = make_float4(1.f, 1.f, 1.f, 1.f);
}

__global__ void concat_copy_kernel(const float* __restrict__ u, const float* __restrict__ it,
                                   float* __restrict__ x, float* __restrict__ acc,
                                   int nu_elems, int total) {
    int i = blockIdx.x * blockDim.x + threadIdx.x;
    if (i >= total) return;
    float v = (i < nu_elems) ? u[i] : it[i - nu_elems];
    x[i] = v;
    acc[i] = v;
}

// ============ CSR build: deterministic histogram radix (R9-proven) ============
__global__ void hist_kernel(const int* __restrict__ h, int* __restrict__ ghist,
                            int E, int EPB, int NB) {
    __shared__ int bins[1024];
    int b = blockIdx.x, tid = threadIdx.x;
    for (int j = tid; j < NB; j += 256) bins[j] = 0;
    __syncthreads();
    int s = b * EPB, e = min(s + EPB, E);
    for (int k = s + tid; k < e; k += 256)
        atomicAdd(&bins[((unsigned)h[k]) >> 8], 1);
    __syncthreads();
    for (int j = tid; j < NB; j += 256) ghist[j * gridDim.x + b] = bins[j];
}

__global__ void btot_kernel(const int* __restrict__ ghist, int* __restrict__ btot) {
    __shared__ int s[256];
    int j = blockIdx.x, tid = threadIdx.x;
    s[tid] = ghist[j * 256 + tid];
    __syncthreads();
    for (int o = 128; o >= 1; o >>= 1) {
        if (tid < o) s[tid] += s[tid + o];
        __syncthreads();
    }
    if (tid == 0) btot[j] = s[0];
}

__global__ void bscan_kernel(const int* __restrict__ btot, int* __restrict__ bbase,
                             int NB, int E) {
    __shared__ int s[1024];
    int tid = threadIdx.x;
    int v = (tid < NB) ? btot[tid] : 0;
    s[tid] = v;
    __syncthreads();
    for (int o = 1; o < 1024; o <<= 1) {
        int a = (tid >= o) ? s[tid - o] : 0;
        __syncthreads();
        s[tid] += a;
        __syncthreads();
    }
    if (tid < NB) bbase[tid] = s[tid] - v;
    if (tid == 0) bbase[NB] = E;
}

__global__ void bofs_kernel(int* __restrict__ ghist, const int* __restrict__ bbase) {
    __shared__ int s[256];
    int j = blockIdx.x, tid = threadIdx.x;
    int v = ghist[j * 256 + tid];
    s[tid] = v;
    __syncthreads();
    for (int o = 1; o < 256; o <<= 1) {
        int a = (tid >= o) ? s[tid - o] : 0;
        __syncthreads();
        s[tid] += a;
        __syncthreads();
    }
    ghist[j * 256 + tid] = bbase[j] + s[tid] - v;
}

__global__ void scatter_kernel(const int* __restrict__ h, const int* __restrict__ t,
                               const int* __restrict__ ghist, unsigned* __restrict__ stg,
                               int E, int EPB, int NB) {
    __shared__ int cur[1024];
    int b = blockIdx.x, tid = threadIdx.x;
    for (int j = tid; j < NB; j += 256) cur[j] = ghist[j * gridDim.x + b];
    __syncthreads();
    int s = b * EPB, e = min(s + EPB, E);
    for (int k = s + tid; k < e; k += 256) {
        unsigned hh = (unsigned)h[k];
        int pos = atomicAdd(&cur[hh >> 8], 1);
        stg[pos] = ((hh & 255u) << 18) | (unsigned)t[k];
    }
}

__global__ void finalize_kernel(const unsigned* __restrict__ stg, const int* __restrict__ bbase,
                                int* __restrict__ off, int* __restrict__ csr_t, int N, int E) {
    __shared__ int cnt[256];
    __shared__ int scn[256];
    int b = blockIdx.x, tid = threadIdx.x;
    int ebeg = bbase[b], eend = bbase[b + 1];
    cnt[tid] = 0;
    __syncthreads();
    for (int k = ebeg + tid; k < eend; k += 256)
        atomicAdd(&cnt[(stg[k] >> 18) & 255u], 1);
    __syncthreads();
    int v = cnt[tid];
    scn[tid] = v;
    __syncthreads();
    for (int o = 1; o < 256; o <<= 1) {
        int a = (tid >= o) ? scn[tid - o] : 0;
        __syncthreads();
        scn[tid] += a;
        __syncthreads();
    }
    int excl = scn[tid] - v;
    int gn = (b << 8) + tid;
    if (gn < N) off[gn] = ebeg + excl;
    if (b == 0 && tid == 0) off[N] = E;
    __syncthreads();
    cnt[tid] = excl;   // reuse as cursor
    __syncthreads();
    for (int k = ebeg + tid; k < eend; k += 256) {
        unsigned en = stg[k];
        int slot = atomicAdd(&cnt[(en >> 18) & 255u], 1);
        csr_t[ebeg + slot] = (int)(en & 0x3FFFFu);
    }
}

// bootstrap: prob=0.25 folded -> dcol0 = 0.5/sqrt(deg)
__global__ void dcol0_kernel(const int* __restrict__ off, float* __restrict__ dcol, int N) {
    int n = blockIdx.x * blockDim.x + threadIdx.x;
    if (n >= N) return;
    float v = 0.5f * rsqrtf((float)(off[n + 1] - off[n]));
    *(float4*)(dcol + (size_t)n * 4) = make_float4(v, v, v, v);
}

// ============ per-layer: xs = f16(x); invnx[n][f] = 1/max(||x_nf||,eps)
__global__ void prep_kernel(const float* __restrict__ x, u16* __restrict__ xs,
                            float* __restrict__ invnx, int total) {
    int i = blockIdx.x * blockDim.x + threadIdx.x;
    if (i >= total) return;
    float v = x[i];
    xs[i] = f2h(v);
    float s = v * v;
#pragma unroll
    for (int o = 8; o >= 1; o >>= 1) s += __shfl_xor(s, o);
    if ((i & 15) == 0) invnx[i >> 4] = 1.0f / fmaxf(sqrtf(s), 1e-12f);
}

// ============ fused message + routing + next-iteration softmax/dcol
// One 64-lane wave per node. lane l: g=l>>3 (8 edge slots), m=l&7 (col octet,
// one uint4 = 8 f16), f=m>>1. Single gather stream: loop1 fetches xs rows and
// stashes the lane's uint4 in LDS; loop2 reads LDS (first 16 edges) and
// recomputes tail = ptanh5(xs * invnx[t]) on the fly (no tailt table).
// Overflow edges (deg>16, ~27% of edges) re-gather xs from global.
// ACC: 0=none, 1=acc+=val, 2=acc=(acc+val)/3 (final mean)
template <bool UNI, bool WOUT, bool ROUTE, int ACC>
__global__ void message_kernel(const int* __restrict__ off, const int* __restrict__ csr_t,
                               float* __restrict__ Acsr, float* __restrict__ prob,
                               const u16* __restrict__ xs, const float* __restrict__ invnx,
                               const float* __restrict__ dcol_in, float* __restrict__ dcol_out,
                               float* __restrict__ out, float* __restrict__ acc, int N) {
    __shared__ uint4 cache[4][16][8];   // [wave][edge slot][col octet] = 8 KB
    int gid = blockIdx.x * blockDim.x + threadIdx.x;
    int n = gid >> 6;
    if (n >= N) return;
    int tid = threadIdx.x;
    int wid = tid >> 6;
    int l = tid & 63;
    int g = l >> 3;
    int m = l & 7;
    unsigned f = (unsigned)(m >> 1);
    int s = off[n], e = off[n + 1];
    unsigned moff = (unsigned)(m << 3);   // u16 index within the 64-wide row

    union U8 { uint4 u; f16 h[8]; };

    float a0 = 0.f, a1 = 0.f, a2 = 0.f, a3 = 0.f;
    float a4 = 0.f, a5 = 0.f, a6 = 0.f, a7 = 0.f;

    auto accum = [&](const U8& w1, const U8& w2, float p1, float p2) {
        a0 = fmaf(p1, (float)w1.h[0], a0); a1 = fmaf(p1, (float)w1.h[1], a1);
        a2 = fmaf(p1, (float)w1.h[2], a2); a3 = fmaf(p1, (float)w1.h[3], a3);
        a4 = fmaf(p1, (float)w1.h[4], a4); a5 = fmaf(p1, (float)w1.h[5], a5);
        a6 = fmaf(p1, (float)w1.h[6], a6); a7 = fmaf(p1, (float)w1.h[7], a7);
        a0 = fmaf(p2, (float)w2.h[0], a0); a1 = fmaf(p2, (float)w2.h[1], a1);
        a2 = fmaf(p2, (float)w2.h[2], a2); a3 = fmaf(p2, (float)w2.h[3], a3);
        a4 = fmaf(p2, (float)w2.h[4], a4); a5 = fmaf(p2, (float)w2.h[5], a5);
        a6 = fmaf(p2, (float)w2.h[6], a6); a7 = fmaf(p2, (float)w2.h[7], a7);
    };

    // ---- loop1, first trip (16 edges): gather + LDS stash ----
    {
        int e1 = s + g, e2 = e1 + 8;
        bool v1 = e1 < e, v2 = e2 < e;
        unsigned c1 = (unsigned)(v1 ? e1 : s);
        unsigned c2 = (unsigned)(v2 ? e2 : s);
        unsigned t1 = (unsigned)csr_t[c1];
        unsigned t2 = (unsigned)csr_t[c2];
        float p1, p2;
        if (UNI) {
            p1 = dcol_in[t1 * 4u + f];
            p2 = dcol_in[t2 * 4u + f];
        } else {
            p1 = prob[c1 * 4u + f] * dcol_in[t1 * 4u + f];
            p2 = prob[c2 * 4u + f] * dcol_in[t2 * 4u + f];
        }
        p1 = v1 ? p1 : 0.f;
        p2 = v2 ? p2 : 0.f;
        U8 w1, w2;
        w1.u = *(const uint4*)(xs + (t1 << 6) + moff);
        w2.u = *(const uint4*)(xs + (t2 << 6) + moff);
        cache[wid][g][m] = w1.u;
        cache[wid][g + 8][m] = w2.u;
        accum(w1, w2, p1, p2);
    }
    // ---- loop1, overflow trips ----
    for (int k = s + 16; k < e; k += 16) {
        int e1 = k + g, e2 = e1 + 8;
        bool v1 = e1 < e, v2 = e2 < e;
        unsigned c1 = (unsigned)(v1 ? e1 : s);
        unsigned c2 = (unsigned)(v2 ? e2 : s);
        unsigned t1 = (unsigned)csr_t[c1];
        unsigned t2 = (unsigned)csr_t[c2];
        float p1, p2;
        if (UNI) {
            p1 = dcol_in[t1 * 4u + f];
            p2 = dcol_in[t2 * 4u + f];
        } else {
            p1 = prob[c1 * 4u + f] * dcol_in[t1 * 4u + f];
            p2 = prob[c2 * 4u + f] * dcol_in[t2 * 4u + f];
        }
        p1 = v1 ? p1 : 0.f;
        p2 = v2 ? p2 : 0.f;
        U8 w1, w2;
        w1.u = *(const uint4*)(xs + (t1 << 6) + moff);
        w2.u = *(const uint4*)(xs + (t2 << 6) + moff);
        accum(w1, w2, p1, p2);
    }

    // combine the 8 edge slots -> every lane holds full sums for its 8 cols
#pragma unroll
    for (int o = 8; o <= 32; o <<= 1) {
        a0 += __shfl_xor(a0, o); a1 += __shfl_xor(a1, o);
        a2 += __shfl_xor(a2, o); a3 += __shfl_xor(a3, o);
        a4 += __shfl_xor(a4, o); a5 += __shfl_xor(a5, o);
        a6 += __shfl_xor(a6, o); a7 += __shfl_xor(a7, o);
    }

    if (WOUT || ACC != 0) {
        float dn = dcol_in[(unsigned)n * 4u + f];
        if (l < 8) {
            unsigned oidx = ((unsigned)n << 6) + moff;
            float4 lo = make_float4(a0 * dn, a1 * dn, a2 * dn, a3 * dn);
            float4 hi = make_float4(a4 * dn, a5 * dn, a6 * dn, a7 * dn);
            if (WOUT) {
                *(float4*)(out + oidx) = lo;
                *(float4*)(out + oidx + 4) = hi;
            }
            if (ACC == 1) {
                float4 c0 = *(const float4*)(acc + oidx);
                float4 c1 = *(const float4*)(acc + oidx + 4);
                *(float4*)(acc + oidx) =
                    make_float4(c0.x + lo.x, c0.y + lo.y, c0.z + lo.z, c0.w + lo.w);
                *(float4*)(acc + oidx + 4) =
                    make_float4(c1.x + hi.x, c1.y + hi.y, c1.z + hi.z, c1.w + hi.w);
            } else if (ACC == 2) {
                const float k3 = 1.0f / 3.0f;
                float4 c0 = *(const float4*)(acc + oidx);
                float4 c1 = *(const float4*)(acc + oidx + 4);
                *(float4*)(acc + oidx) =
                    make_float4((c0.x + lo.x) * k3, (c0.y + lo.y) * k3,
                                (c0.z + lo.z) * k3, (c0.w + lo.w) * k3);
                *(float4*)(acc + oidx + 4) =
                    make_float4((c1.x + hi.x) * k3, (c1.y + hi.y) * k3,
                                (c1.z + hi.z) * k3, (c1.w + hi.w) * k3);
            }
        }
    }
    if (!ROUTE) return;

    // head = l2norm per factor (dcol[n] scale-invariant); 16 cols = this lane's
    // 8 + partner lane's 8 (xor 1)
    float ss = a0 * a0 + a1 * a1 + a2 * a2 + a3 * a3
             + a4 * a4 + a5 * a5 + a6 * a6 + a7 * a7;
    ss += __shfl_xor(ss, 1);
    float inv = 1.0f / fmaxf(sqrtf(ss), 1e-12f);
    float hv[8];
    hv[0] = a0 * inv; hv[1] = a1 * inv; hv[2] = a2 * inv; hv[3] = a3 * inv;
    hv[4] = a4 * inv; hv[5] = a5 * inv; hv[6] = a6 * inv; hv[7] = a7 * inv;

    // tail-dot: sum_i hv[i] * ptanh5(xs_i * invnx)  (8 cols of this lane)
    auto tdot = [&](const U8& w, float iv) -> float {
        float d = 0.f;
#pragma unroll
        for (int i = 0; i < 8; ++i)
            d = fmaf(hv[i], ptanh5((float)w.h[i] * iv), d);
        return d;
    };

    float rowsumf = 0.f;

    auto route = [&](int kbase, const U8& w1, const U8& w2,
                     unsigned t1, unsigned t2) {
        int e1 = kbase + g, e2 = e1 + 8;
        bool v1 = e1 < e, v2 = e2 < e;
        unsigned c1 = (unsigned)(v1 ? e1 : s);
        unsigned c2 = (unsigned)(v2 ? e2 : s);
        float iv1 = invnx[t1 * 4u + f];
        float iv2 = invnx[t2 * 4u + f];
        float d1 = tdot(w1, iv1);
        float d2 = tdot(w2, iv2);
        d1 += __shfl_xor(d1, 1);   // partner lane completes the 16-col dot
        d2 += __shfl_xor(d2, 1);
        unsigned ai1 = c1 * 4u + f;
        unsigned ai2 = c2 * 4u + f;
        float na1 = Acsr[ai1] + d1;
        float na2 = Acsr[ai2] + d2;
        // softmax over the 4 factors (xor 2 then xor 4 across f lanes)
        float ex1 = __expf(na1);
        float ex2 = __expf(na2);
        float se1 = ex1 + __shfl_xor(ex1, 2); se1 += __shfl_xor(se1, 4);
        float se2 = ex2 + __shfl_xor(ex2, 2); se2 += __shfl_xor(se2, 4);
        float p1 = ex1 * __builtin_amdgcn_rcpf(se1);
        float p2 = ex2 * __builtin_amdgcn_rcpf(se2);
        if ((m & 1) == 0) {
            if (v1) { Acsr[ai1] = na1; prob[ai1] = p1; }
            if (v2) { Acsr[ai2] = na2; prob[ai2] = p2; }
        }
        rowsumf += (v1 ? p1 : 0.f) + (v2 ? p2 : 0.f);
    };

    // ---- loop2, first trip: rows from LDS (zero global gather) ----
    {
        int e1 = s + g, e2 = e1 + 8;
        unsigned c1 = (unsigned)((e1 < e) ? e1 : s);
        unsigned c2 = (unsigned)((e2 < e) ? e2 : s);
        unsigned t1 = (unsigned)csr_t[c1];
        unsigned t2 = (unsigned)csr_t[c2];
        U8 w1, w2;
        w1.u = cache[wid][g][m];
        w2.u = cache[wid][g + 8][m];
        route(s, w1, w2, t1, t2);
    }
    // ---- loop2, overflow trips: re-gather xs ----
    for (int k = s + 16; k < e; k += 16) {
        int e1 = k + g, e2 = e1 + 8;
        unsigned c1 = (unsigned)((e1 < e) ? e1 : s);
        unsigned c2 = (unsigned)((e2 < e) ? e2 : s);
        unsigned t1 = (unsigned)csr_t[c1];
        unsigned t2 = (unsigned)csr_t[c2];
        U8 w1, w2;
        w1.u = *(const uint4*)(xs + (t1 << 6) + moff);
        w2.u = *(const uint4*)(xs + (t2 << 6) + moff);
        route(k, w1, w2, t1, t2);
    }

    // sum over the 8 slots
    rowsumf += __shfl_xor(rowsumf, 8);
    rowsumf += __shfl_xor(rowsumf, 16);
    rowsumf += __shfl_xor(rowsumf, 32);
    if (l < 8 && (m & 1) == 0) dcol_out[(unsigned)n * 4u + f] = rsqrtf(rowsumf);
}

extern "C" void kernel_launch(void* const* d_in, const int* in_sizes, int n_in,
                              void* d_out, int out_size, void* d_ws, size_t ws_size,
                              hipStream_t stream) {
    const float* user_emb = (const float*)d_in[0];
    const float* item_emb = (const float*)d_in[1];
    const int* h = (const int*)d_in[2];
    const int* t = (const int*)d_in[3];

    const int nu_elems = in_sizes[0];
    const int ni_elems = in_sizes[1];
    const int total = nu_elems + ni_elems;   // N * 64
    const int N = total / DEMB;
    const int E = in_sizes[2];
    const int NB = (N + 255) >> 8;           // buckets (<= 1024)
    const int NBLK = 256;
    const int EPB = (E + NBLK - 1) / NBLK;

    float* acc = (float*)d_out;

    // ---- workspace layout ----
    float* x     = (float*)d_ws;                    // total f32
    float* out   = x + (size_t)total;               // total f32
    float* Acsr  = out + (size_t)total;             // 4E f32
    float* prob  = Acsr + (size_t)4 * E;            // 4E f32 (first E aliased as stg)
    float* dcolA = prob + (size_t)4 * E;            // 4N f32
    float* dcolB = dcolA + (size_t)4 * N;           // 4N f32
    float* invnx = dcolB + (size_t)4 * N;           // 4N f32
    u16* xs      = (u16*)(invnx + (size_t)4 * N);   // total u16 (f16 bits)
    int* ghist   = (int*)(xs + (size_t)total);      // NB*256
    int* btot    = ghist + (size_t)NB * 256;        // NB
    int* bbase   = btot + ((NB + 3) & ~3);          // NB+1
    int* off     = bbase + ((NB + 5) & ~3);         // N+1
    int* csr_t   = off + ((N + 4) & ~3);            // E
    unsigned* stg = (unsigned*)prob;                // E (time-disjoint with prob)

    const int BLK = 256;
    const int gE = (E + BLK - 1) / BLK;
    const int gTot = (total + BLK - 1) / BLK;
    const int gN = (N + BLK - 1) / BLK;
    const int gNodeWave = (N * 64 + BLK - 1) / BLK;

    concat_copy_kernel<<<gTot, BLK, 0, stream>>>(user_emb, item_emb, x, acc, nu_elems, total);

    // CSR build (deterministic, no contended global atomics)
    hist_kernel<<<NBLK, 256, 0, stream>>>(h, ghist, E, EPB, NB);
    btot_kernel<<<NB, 256, 0, stream>>>(ghist, btot);
    bscan_kernel<<<1, 1024, 0, stream>>>(btot, bbase, NB, E);
    bofs_kernel<<<NB, 256, 0, stream>>>(ghist, bbase);
    scatter_kernel<<<NBLK, 256, 0, stream>>>(h, t, ghist, stg, E, EPB, NB);
    finalize_kernel<<<NB, 256, 0, stream>>>(stg, bbase, off, csr_t, N, E);

    init_A_kernel<<<gE, BLK, 0, stream>>>((float4*)Acsr, E);
    dcol0_kernel<<<gN, BLK, 0, stream>>>(off, dcolA, N);

    // ---- layer 0 ----
    prep_kernel<<<gTot, BLK, 0, stream>>>(x, xs, invnx, total);
    message_kernel<true, false, true, 0><<<gNodeWave, BLK, 0, stream>>>(
        off, csr_t, Acsr, prob, xs, invnx, dcolA, dcolB, out, acc, N);
    message_kernel<false, true, true, 1><<<gNodeWave, BLK, 0, stream>>>(
        off, csr_t, Acsr, prob, xs, invnx, dcolB, dcolA, out, acc, N);

    // ---- layer 1 ----
    prep_kernel<<<gTot, BLK, 0, stream>>>(out, xs, invnx, total);
    message_kernel<false, false, true, 0><<<gNodeWave, BLK, 0, stream>>>(
        off, csr_t, Acsr, prob, xs, invnx, dcolA, dcolB, x, acc, N);
    message_kernel<false, false, false, 2><<<gNodeWave, BLK, 0, stream>>>(
        off, csr_t, Acsr, prob, xs, invnx, dcolB, dcolA, x, acc, N);
}

// Round 18
// 536.488 us; speedup vs baseline: 1.2405x; 1.0205x over previous
//
#include <hip/hip_runtime.h>
#include <hip/hip_bf16.h>

#define DEMB 64
typedef unsigned short u16;
typedef _Float16 f16;
typedef _Float16 h2 __attribute__((ext_vector_type(2)));

#if defined(__has_builtin)
#if __has_builtin(__builtin_amdgcn_fdot2)
#define USE_FDOT2 1
#endif
#endif

__device__ __forceinline__ u16 f2h(float f) {
    union { f16 h; u16 u; } c; c.h = (f16)f; return c.u;
}

// odd 7th-order minimax tanh on [-1.02, 1.02], abs err <= ~3e-4 (f32 scalar)
__device__ __forceinline__ float ptanh5(float a) {
    float a2 = a * a;
    float t = fmaf(a2, -0.030095f, 0.124066f);
    t = fmaf(a2, t, -0.332377f);
    t = fmaf(a2, t, 1.0f);
    return a * t;
}

__global__ void init_A_kernel(float4* __restrict__ A, int E) {
    int e = blockIdx.x * blockDim.x + threadIdx.x;
    if (e < E) A[e] = make_float4(1.f, 1.f, 1.f, 1.f);
}

__global__ void concat_copy_kernel(const float* __restrict__ u, const float* __restrict__ it,
                                   float* __restrict__ x, float* __restrict__ acc,
                                   int nu_elems, int total) {
    int i = blockIdx.x * blockDim.x + threadIdx.x;
    if (i >= total) return;
    float v = (i < nu_elems) ? u[i] : it[i - nu_elems];
    x[i] = v;
    acc[i] = v;
}

// ============ CSR build: deterministic histogram radix (R9-proven) ============
__global__ void hist_kernel(const int* __restrict__ h, int* __restrict__ ghist,
                            int E, int EPB, int NB) {
    __shared__ int bins[1024];
    int b = blockIdx.x, tid = threadIdx.x;
    for (int j = tid; j < NB; j += 256) bins[j] = 0;
    __syncthreads();
    int s = b * EPB, e = min(s + EPB, E);
    for (int k = s + tid; k < e; k += 256)
        atomicAdd(&bins[((unsigned)h[k]) >> 8], 1);
    __syncthreads();
    for (int j = tid; j < NB; j += 256) ghist[j * gridDim.x + b] = bins[j];
}

__global__ void btot_kernel(const int* __restrict__ ghist, int* __restrict__ btot) {
    __shared__ int s[256];
    int j = blockIdx.x, tid = threadIdx.x;
    s[tid] = ghist[j * 256 + tid];
    __syncthreads();
    for (int o = 128; o >= 1; o >>= 1) {
        if (tid < o) s[tid] += s[tid + o];
        __syncthreads();
    }
    if (tid == 0) btot[j] = s[0];
}

__global__ void bscan_kernel(const int* __restrict__ btot, int* __restrict__ bbase,
                             int NB, int E) {
    __shared__ int s[1024];
    int tid = threadIdx.x;
    int v = (tid < NB) ? btot[tid] : 0;
    s[tid] = v;
    __syncthreads();
    for (int o = 1; o < 1024; o <<= 1) {
        int a = (tid >= o) ? s[tid - o] : 0;
        __syncthreads();
        s[tid] += a;
        __syncthreads();
    }
    if (tid < NB) bbase[tid] = s[tid] - v;
    if (tid == 0) bbase[NB] = E;
}

__global__ void bofs_kernel(int* __restrict__ ghist, const int* __restrict__ bbase) {
    __shared__ int s[256];
    int j = blockIdx.x, tid = threadIdx.x;
    int v = ghist[j * 256 + tid];
    s[tid] = v;
    __syncthreads();
    for (int o = 1; o < 256; o <<= 1) {
        int a = (tid >= o) ? s[tid - o] : 0;
        __syncthreads();
        s[tid] += a;
        __syncthreads();
    }
    ghist[j * 256 + tid] = bbase[j] + s[tid] - v;
}

__global__ void scatter_kernel(const int* __restrict__ h, const int* __restrict__ t,
                               const int* __restrict__ ghist, unsigned* __restrict__ stg,
                               int E, int EPB, int NB) {
    __shared__ int cur[1024];
    int b = blockIdx.x, tid = threadIdx.x;
    for (int j = tid; j < NB; j += 256) cur[j] = ghist[j * gridDim.x + b];
    __syncthreads();
    int s = b * EPB, e = min(s + EPB, E);
    for (int k = s + tid; k < e; k += 256) {
        unsigned hh = (unsigned)h[k];
        int pos = atomicAdd(&cur[hh >> 8], 1);
        stg[pos] = ((hh & 255u) << 18) | (unsigned)t[k];
    }
}

__global__ void finalize_kernel(const unsigned* __restrict__ stg, const int* __restrict__ bbase,
                                int* __restrict__ off, int* __restrict__ csr_t, int N, int E) {
    __shared__ int cnt[256];
    __shared__ int scn[256];
    int b = blockIdx.x, tid = threadIdx.x;
    int ebeg = bbase[b], eend = bbase[b + 1];
    cnt[tid] = 0;
    __syncthreads();
    for (int k = ebeg + tid; k < eend; k += 256)
        atomicAdd(&cnt[(stg[k] >> 18) & 255u], 1);
    __syncthreads();
    int v = cnt[tid];
    scn[tid] = v;
    __syncthreads();
    for (int o = 1; o < 256; o <<= 1) {
        int a = (tid >= o) ? scn[tid - o] : 0;
        __syncthreads();
        scn[tid] += a;
        __syncthreads();
    }
    int excl = scn[tid] - v;
    int gn = (b << 8) + tid;
    if (gn < N) off[gn] = ebeg + excl;
    if (b == 0 && tid == 0) off[N] = E;
    __syncthreads();
    cnt[tid] = excl;   // reuse as cursor
    __syncthreads();
    for (int k = ebeg + tid; k < eend; k += 256) {
        unsigned en = stg[k];
        int slot = atomicAdd(&cnt[(en >> 18) & 255u], 1);
        csr_t[ebeg + slot] = (int)(en & 0x3FFFFu);
    }
}

// bootstrap: prob=0.25 folded -> dcol0 = 0.5/sqrt(deg)
__global__ void dcol0_kernel(const int* __restrict__ off, float* __restrict__ dcol, int N) {
    int n = blockIdx.x * blockDim.x + threadIdx.x;
    if (n >= N) return;
    float v = 0.5f * rsqrtf((float)(off[n + 1] - off[n]));
    *(float4*)(dcol + (size_t)n * 4) = make_float4(v, v, v, v);
}

// ============ per-layer: xs = f16(x); invnx[n][f] = 1/max(||x_nf||,eps)
__global__ void prep_kernel(const float* __restrict__ x, u16* __restrict__ xs,
                            float* __restrict__ invnx, int total) {
    int i = blockIdx.x * blockDim.x + threadIdx.x;
    if (i >= total) return;
    float v = x[i];
    xs[i] = f2h(v);
    float s = v * v;
#pragma unroll
    for (int o = 8; o >= 1; o >>= 1) s += __shfl_xor(s, o);
    if ((i & 15) == 0) invnx[i >> 4] = 1.0f / fmaxf(sqrtf(s), 1e-12f);
}

// ============ fused message + routing + next-iteration softmax/dcol
// One 64-lane wave per node. lane l: g=l>>3 (8 edge slots), m=l&7 (col octet,
// one uint4 = 8 f16), f=m>>1. Single gather stream: loop1 fetches xs rows and
// stashes the lane's uint4 in LDS; loop2 reads LDS (first 16 edges) and
// recomputes tail = tanh(xs*invnx[t]) via PACKED f16 math (v_pk_fma_f16) with
// v_dot2_f32_f16 for the head-dot. Overflow edges (deg>16) re-gather xs.
// ACC: 0=none, 1=acc+=val, 2=acc=(acc+val)/3 (final mean)
template <bool UNI, bool WOUT, bool ROUTE, int ACC>
__global__ void message_kernel(const int* __restrict__ off, const int* __restrict__ csr_t,
                               float* __restrict__ Acsr, float* __restrict__ prob,
                               const u16* __restrict__ xs, const float* __restrict__ invnx,
                               const float* __restrict__ dcol_in, float* __restrict__ dcol_out,
                               float* __restrict__ out, float* __restrict__ acc, int N) {
    __shared__ uint4 cache[4][16][8];   // [wave][edge slot][col octet] = 8 KB
    int gid = blockIdx.x * blockDim.x + threadIdx.x;
    int n = gid >> 6;
    if (n >= N) return;
    int tid = threadIdx.x;
    int wid = tid >> 6;
    int l = tid & 63;
    int g = l >> 3;
    int m = l & 7;
    unsigned f = (unsigned)(m >> 1);
    int s = off[n], e = off[n + 1];
    unsigned moff = (unsigned)(m << 3);   // u16 index within the 64-wide row

    union U8 { uint4 u; f16 h[8]; h2 p[4]; };

    float a0 = 0.f, a1 = 0.f, a2 = 0.f, a3 = 0.f;
    float a4 = 0.f, a5 = 0.f, a6 = 0.f, a7 = 0.f;

    auto accum = [&](const U8& w1, const U8& w2, float p1, float p2) {
        a0 = fmaf(p1, (float)w1.h[0], a0); a1 = fmaf(p1, (float)w1.h[1], a1);
        a2 = fmaf(p1, (float)w1.h[2], a2); a3 = fmaf(p1, (float)w1.h[3], a3);
        a4 = fmaf(p1, (float)w1.h[4], a4); a5 = fmaf(p1, (float)w1.h[5], a5);
        a6 = fmaf(p1, (float)w1.h[6], a6); a7 = fmaf(p1, (float)w1.h[7], a7);
        a0 = fmaf(p2, (float)w2.h[0], a0); a1 = fmaf(p2, (float)w2.h[1], a1);
        a2 = fmaf(p2, (float)w2.h[2], a2); a3 = fmaf(p2, (float)w2.h[3], a3);
        a4 = fmaf(p2, (float)w2.h[4], a4); a5 = fmaf(p2, (float)w2.h[5], a5);
        a6 = fmaf(p2, (float)w2.h[6], a6); a7 = fmaf(p2, (float)w2.h[7], a7);
    };

    // ---- loop1, first trip (16 edges): gather + LDS stash ----
    {
        int e1 = s + g, e2 = e1 + 8;
        bool v1 = e1 < e, v2 = e2 < e;
        unsigned c1 = (unsigned)(v1 ? e1 : s);
        unsigned c2 = (unsigned)(v2 ? e2 : s);
        unsigned t1 = (unsigned)csr_t[c1];
        unsigned t2 = (unsigned)csr_t[c2];
        float p1, p2;
        if (UNI) {
            p1 = dcol_in[t1 * 4u + f];
            p2 = dcol_in[t2 * 4u + f];
        } else {
            p1 = prob[c1 * 4u + f] * dcol_in[t1 * 4u + f];
            p2 = prob[c2 * 4u + f] * dcol_in[t2 * 4u + f];
        }
        p1 = v1 ? p1 : 0.f;
        p2 = v2 ? p2 : 0.f;
        U8 w1, w2;
        w1.u = *(const uint4*)(xs + (t1 << 6) + moff);
        w2.u = *(const uint4*)(xs + (t2 << 6) + moff);
        cache[wid][g][m] = w1.u;
        cache[wid][g + 8][m] = w2.u;
        accum(w1, w2, p1, p2);
    }
    // ---- loop1, overflow trips ----
    for (int k = s + 16; k < e; k += 16) {
        int e1 = k + g, e2 = e1 + 8;
        bool v1 = e1 < e, v2 = e2 < e;
        unsigned c1 = (unsigned)(v1 ? e1 : s);
        unsigned c2 = (unsigned)(v2 ? e2 : s);
        unsigned t1 = (unsigned)csr_t[c1];
        unsigned t2 = (unsigned)csr_t[c2];
        float p1, p2;
        if (UNI) {
            p1 = dcol_in[t1 * 4u + f];
            p2 = dcol_in[t2 * 4u + f];
        } else {
            p1 = prob[c1 * 4u + f] * dcol_in[t1 * 4u + f];
            p2 = prob[c2 * 4u + f] * dcol_in[t2 * 4u + f];
        }
        p1 = v1 ? p1 : 0.f;
        p2 = v2 ? p2 : 0.f;
        U8 w1, w2;
        w1.u = *(const uint4*)(xs + (t1 << 6) + moff);
        w2.u = *(const uint4*)(xs + (t2 << 6) + moff);
        accum(w1, w2, p1, p2);
    }

    // combine the 8 edge slots -> every lane holds full sums for its 8 cols
#pragma unroll
    for (int o = 8; o <= 32; o <<= 1) {
        a0 += __shfl_xor(a0, o); a1 += __shfl_xor(a1, o);
        a2 += __shfl_xor(a2, o); a3 += __shfl_xor(a3, o);
        a4 += __shfl_xor(a4, o); a5 += __shfl_xor(a5, o);
        a6 += __shfl_xor(a6, o); a7 += __shfl_xor(a7, o);
    }

    if (WOUT || ACC != 0) {
        float dn = dcol_in[(unsigned)n * 4u + f];
        if (l < 8) {
            unsigned oidx = ((unsigned)n << 6) + moff;
            float4 lo = make_float4(a0 * dn, a1 * dn, a2 * dn, a3 * dn);
            float4 hi = make_float4(a4 * dn, a5 * dn, a6 * dn, a7 * dn);
            if (WOUT) {
                *(float4*)(out + oidx) = lo;
                *(float4*)(out + oidx + 4) = hi;
            }
            if (ACC == 1) {
                float4 c0 = *(const float4*)(acc + oidx);
                float4 c1 = *(const float4*)(acc + oidx + 4);
                *(float4*)(acc + oidx) =
                    make_float4(c0.x + lo.x, c0.y + lo.y, c0.z + lo.z, c0.w + lo.w);
                *(float4*)(acc + oidx + 4) =
                    make_float4(c1.x + hi.x, c1.y + hi.y, c1.z + hi.z, c1.w + hi.w);
            } else if (ACC == 2) {
                const float k3 = 1.0f / 3.0f;
                float4 c0 = *(const float4*)(acc + oidx);
                float4 c1 = *(const float4*)(acc + oidx + 4);
                *(float4*)(acc + oidx) =
                    make_float4((c0.x + lo.x) * k3, (c0.y + lo.y) * k3,
                                (c0.z + lo.z) * k3, (c0.w + lo.w) * k3);
                *(float4*)(acc + oidx + 4) =
                    make_float4((c1.x + hi.x) * k3, (c1.y + hi.y) * k3,
                                (c1.z + hi.z) * k3, (c1.w + hi.w) * k3);
            }
        }
    }
    if (!ROUTE) return;

    // head = l2norm per factor (dcol[n] scale-invariant); 16 cols = this lane's
    // 8 + partner lane's 8 (xor 1); pack head into f16x2 for dot2
    float ss = a0 * a0 + a1 * a1 + a2 * a2 + a3 * a3
             + a4 * a4 + a5 * a5 + a6 * a6 + a7 * a7;
    ss += __shfl_xor(ss, 1);
    float inv = 1.0f / fmaxf(sqrtf(ss), 1e-12f);
    h2 hp[4];
    hp[0] = h2{(f16)(a0 * inv), (f16)(a1 * inv)};
    hp[1] = h2{(f16)(a2 * inv), (f16)(a3 * inv)};
    hp[2] = h2{(f16)(a4 * inv), (f16)(a5 * inv)};
    hp[3] = h2{(f16)(a6 * inv), (f16)(a7 * inv)};
#ifndef USE_FDOT2
    float hv[8];
    hv[0] = a0 * inv; hv[1] = a1 * inv; hv[2] = a2 * inv; hv[3] = a3 * inv;
    hv[4] = a4 * inv; hv[5] = a5 * inv; hv[6] = a6 * inv; hv[7] = a7 * inv;
#endif

    const h2 C3 = {(f16)-0.030095f, (f16)-0.030095f};
    const h2 C2 = {(f16)0.124066f, (f16)0.124066f};
    const h2 C1 = {(f16)-0.332377f, (f16)-0.332377f};
    const h2 C0 = {(f16)1.0f, (f16)1.0f};

    // tail-dot: sum_i hp[i] . tanh_pk(xs_pair * iv)   (packed f16 poly)
    auto tdot = [&](const U8& w, float ivf) -> float {
        f16 ivh = (f16)ivf;
        h2 iv2 = {ivh, ivh};
        float d = 0.f;
#pragma unroll
        for (int i = 0; i < 4; ++i) {
            h2 a = w.p[i] * iv2;
            h2 aa = a * a;
            h2 t = aa * C3 + C2;
            t = aa * t + C1;
            t = aa * t + C0;
            h2 r = a * t;
#ifdef USE_FDOT2
            d = __builtin_amdgcn_fdot2(hp[i], r, d, false);
#else
            d = fmaf(hv[2 * i], (float)r.x, d);
            d = fmaf(hv[2 * i + 1], (float)r.y, d);
#endif
        }
        return d;
    };

    float rowsumf = 0.f;

    auto route = [&](int kbase, const U8& w1, const U8& w2,
                     unsigned t1, unsigned t2) {
        int e1 = kbase + g, e2 = e1 + 8;
        bool v1 = e1 < e, v2 = e2 < e;
        unsigned c1 = (unsigned)(v1 ? e1 : s);
        unsigned c2 = (unsigned)(v2 ? e2 : s);
        float iv1 = invnx[t1 * 4u + f];
        float iv2 = invnx[t2 * 4u + f];
        float d1 = tdot(w1, iv1);
        float d2 = tdot(w2, iv2);
        d1 += __shfl_xor(d1, 1);   // partner lane completes the 16-col dot
        d2 += __shfl_xor(d2, 1);
        unsigned ai1 = c1 * 4u + f;
        unsigned ai2 = c2 * 4u + f;
        float na1 = Acsr[ai1] + d1;
        float na2 = Acsr[ai2] + d2;
        // softmax over the 4 factors (xor 2 then xor 4 across f lanes)
        float ex1 = __expf(na1);
        float ex2 = __expf(na2);
        float se1 = ex1 + __shfl_xor(ex1, 2); se1 += __shfl_xor(se1, 4);
        float se2 = ex2 + __shfl_xor(ex2, 2); se2 += __shfl_xor(se2, 4);
        float p1 = ex1 * __builtin_amdgcn_rcpf(se1);
        float p2 = ex2 * __builtin_amdgcn_rcpf(se2);
        if ((m & 1) == 0) {
            if (v1) { Acsr[ai1] = na1; prob[ai1] = p1; }
            if (v2) { Acsr[ai2] = na2; prob[ai2] = p2; }
        }
        rowsumf += (v1 ? p1 : 0.f) + (v2 ? p2 : 0.f);
    };

    // ---- loop2, first trip: rows from LDS (zero global gather) ----
    {
        int e1 = s + g, e2 = e1 + 8;
        unsigned c1 = (unsigned)((e1 < e) ? e1 : s);
        unsigned c2 = (unsigned)((e2 < e) ? e2 : s);
        unsigned t1 = (unsigned)csr_t[c1];
        unsigned t2 = (unsigned)csr_t[c2];
        U8 w1, w2;
        w1.u = cache[wid][g][m];
        w2.u = cache[wid][g + 8][m];
        route(s, w1, w2, t1, t2);
    }
    // ---- loop2, overflow trips: re-gather xs ----
    for (int k = s + 16; k < e; k += 16) {
        int e1 = k + g, e2 = e1 + 8;
        unsigned c1 = (unsigned)((e1 < e) ? e1 : s);
        unsigned c2 = (unsigned)((e2 < e) ? e2 : s);
        unsigned t1 = (unsigned)csr_t[c1];
        unsigned t2 = (unsigned)csr_t[c2];
        U8 w1, w2;
        w1.u = *(const uint4*)(xs + (t1 << 6) + moff);
        w2.u = *(const uint4*)(xs + (t2 << 6) + moff);
        route(k, w1, w2, t1, t2);
    }

    // sum over the 8 slots
    rowsumf += __shfl_xor(rowsumf, 8);
    rowsumf += __shfl_xor(rowsumf, 16);
    rowsumf += __shfl_xor(rowsumf, 32);
    if (l < 8 && (m & 1) == 0) dcol_out[(unsigned)n * 4u + f] = rsqrtf(rowsumf);
}

extern "C" void kernel_launch(void* const* d_in, const int* in_sizes, int n_in,
                              void* d_out, int out_size, void* d_ws, size_t ws_size,
                              hipStream_t stream) {
    const float* user_emb = (const float*)d_in[0];
    const float* item_emb = (const float*)d_in[1];
    const int* h = (const int*)d_in[2];
    const int* t = (const int*)d_in[3];

    const int nu_elems = in_sizes[0];
    const int ni_elems = in_sizes[1];
    const int total = nu_elems + ni_elems;   // N * 64
    const int N = total / DEMB;
    const int E = in_sizes[2];
    const int NB = (N + 255) >> 8;           // buckets (<= 1024)
    const int NBLK = 256;
    const int EPB = (E + NBLK - 1) / NBLK;

    float* acc = (float*)d_out;

    // ---- workspace layout ----
    float* x     = (float*)d_ws;                    // total f32
    float* out   = x + (size_t)total;               // total f32
    float* Acsr  = out + (size_t)total;             // 4E f32
    float* prob  = Acsr + (size_t)4 * E;            // 4E f32 (first E aliased as stg)
    float* dcolA = prob + (size_t)4 * E;            // 4N f32
    float* dcolB = dcolA + (size_t)4 * N;           // 4N f32
    float* invnx = dcolB + (size_t)4 * N;           // 4N f32
    u16* xs      = (u16*)(invnx + (size_t)4 * N);   // total u16 (f16 bits)
    int* ghist   = (int*)(xs + (size_t)total);      // NB*256
    int* btot    = ghist + (size_t)NB * 256;        // NB
    int* bbase   = btot + ((NB + 3) & ~3);          // NB+1
    int* off     = bbase + ((NB + 5) & ~3);         // N+1
    int* csr_t   = off + ((N + 4) & ~3);            // E
    unsigned* stg = (unsigned*)prob;                // E (time-disjoint with prob)

    const int BLK = 256;
    const int gE = (E + BLK - 1) / BLK;
    const int gTot = (total + BLK - 1) / BLK;
    const int gN = (N + BLK - 1) / BLK;
    const int gNodeWave = (N * 64 + BLK - 1) / BLK;

    concat_copy_kernel<<<gTot, BLK, 0, stream>>>(user_emb, item_emb, x, acc, nu_elems, total);

    // CSR build (deterministic, no contended global atomics)
    hist_kernel<<<NBLK, 256, 0, stream>>>(h, ghist, E, EPB, NB);
    btot_kernel<<<NB, 256, 0, stream>>>(ghist, btot);
    bscan_kernel<<<1, 1024, 0, stream>>>(btot, bbase, NB, E);
    bofs_kernel<<<NB, 256, 0, stream>>>(ghist, bbase);
    scatter_kernel<<<NBLK, 256, 0, stream>>>(h, t, ghist, stg, E, EPB, NB);
    finalize_kernel<<<NB, 256, 0, stream>>>(stg, bbase, off, csr_t, N, E);

    init_A_kernel<<<gE, BLK, 0, stream>>>((float4*)Acsr, E);
    dcol0_kernel<<<gN, BLK, 0, stream>>>(off, dcolA, N);

    // ---- layer 0 ----
    prep_kernel<<<gTot, BLK, 0, stream>>>(x, xs, invnx, total);
    message_kernel<true, false, true, 0><<<gNodeWave, BLK, 0, stream>>>(
        off, csr_t, Acsr, prob, xs, invnx, dcolA, dcolB, out, acc, N);
    message_kernel<false, true, true, 1><<<gNodeWave, BLK, 0, stream>>>(
        off, csr_t, Acsr, prob, xs, invnx, dcolB, dcolA, out, acc, N);

    // ---- layer 1 ----
    prep_kernel<<<gTot, BLK, 0, stream>>>(out, xs, invnx, total);
    message_kernel<false, false, true, 0><<<gNodeWave, BLK, 0, stream>>>(
        off, csr_t, Acsr, prob, xs, invnx, dcolA, dcolB, x, acc, N);
    message_kernel<false, false, false, 2><<<gNodeWave, BLK, 0, stream>>>(
        off, csr_t, Acsr, prob, xs, invnx, dcolB, dcolA, x, acc, N);
}

// Round 19
// 534.411 us; speedup vs baseline: 1.2453x; 1.0039x over previous
//
#include <hip/hip_runtime.h>
#include <hip/hip_bf16.h>

#define DEMB 64
typedef unsigned short u16;
typedef _Float16 f16;
typedef _Float16 h2 __attribute__((ext_vector_type(2)));

#if defined(__has_builtin)
#if __has_builtin(__builtin_amdgcn_fdot2)
#define USE_FDOT2 1
#endif
#endif

__device__ __forceinline__ u16 f2h(float f) {
    union { f16 h; u16 u; } c; c.h = (f16)f; return c.u;
}

// odd 7th-order minimax tanh on [-1.02, 1.02], abs err <= ~3e-4 (f32 scalar)
__device__ __forceinline__ float ptanh5(float a) {
    float a2 = a * a;
    float t = fmaf(a2, -0.030095f, 0.124066f);
    t = fmaf(a2, t, -0.332377f);
    t = fmaf(a2, t, 1.0f);
    return a * t;
}

__global__ void init_A_kernel(float4* __restrict__ A, int E) {
    int e = blockIdx.x * blockDim.x + threadIdx.x;
    if (e < E) A[e] = make_float4(1.f, 1.f, 1.f, 1.f);
}

__global__ void concat_copy_kernel(const float* __restrict__ u, const float* __restrict__ it,
                                   float* __restrict__ x, float* __restrict__ acc,
                                   int nu_elems, int total) {
    int i = blockIdx.x * blockDim.x + threadIdx.x;
    if (i >= total) return;
    float v = (i < nu_elems) ? u[i] : it[i - nu_elems];
    x[i] = v;
    acc[i] = v;
}

// ============ CSR build: deterministic histogram radix (R9-proven) ============
__global__ void hist_kernel(const int* __restrict__ h, int* __restrict__ ghist,
                            int E, int EPB, int NB) {
    __shared__ int bins[1024];
    int b = blockIdx.x, tid = threadIdx.x;
    for (int j = tid; j < NB; j += 256) bins[j] = 0;
    __syncthreads();
    int s = b * EPB, e = min(s + EPB, E);
    for (int k = s + tid; k < e; k += 256)
        atomicAdd(&bins[((unsigned)h[k]) >> 8], 1);
    __syncthreads();
    for (int j = tid; j < NB; j += 256) ghist[j * gridDim.x + b] = bins[j];
}

__global__ void btot_kernel(const int* __restrict__ ghist, int* __restrict__ btot) {
    __shared__ int s[256];
    int j = blockIdx.x, tid = threadIdx.x;
    s[tid] = ghist[j * 256 + tid];
    __syncthreads();
    for (int o = 128; o >= 1; o >>= 1) {
        if (tid < o) s[tid] += s[tid + o];
        __syncthreads();
    }
    if (tid == 0) btot[j] = s[0];
}

__global__ void bscan_kernel(const int* __restrict__ btot, int* __restrict__ bbase,
                             int NB, int E) {
    __shared__ int s[1024];
    int tid = threadIdx.x;
    int v = (tid < NB) ? btot[tid] : 0;
    s[tid] = v;
    __syncthreads();
    for (int o = 1; o < 1024; o <<= 1) {
        int a = (tid >= o) ? s[tid - o] : 0;
        __syncthreads();
        s[tid] += a;
        __syncthreads();
    }
    if (tid < NB) bbase[tid] = s[tid] - v;
    if (tid == 0) bbase[NB] = E;
}

__global__ void bofs_kernel(int* __restrict__ ghist, const int* __restrict__ bbase) {
    __shared__ int s[256];
    int j = blockIdx.x, tid = threadIdx.x;
    int v = ghist[j * 256 + tid];
    s[tid] = v;
    __syncthreads();
    for (int o = 1; o < 256; o <<= 1) {
        int a = (tid >= o) ? s[tid - o] : 0;
        __syncthreads();
        s[tid] += a;
        __syncthreads();
    }
    ghist[j * 256 + tid] = bbase[j] + s[tid] - v;
}

__global__ void scatter_kernel(const int* __restrict__ h, const int* __restrict__ t,
                               const int* __restrict__ ghist, unsigned* __restrict__ stg,
                               int E, int EPB, int NB) {
    __shared__ int cur[1024];
    int b = blockIdx.x, tid = threadIdx.x;
    for (int j = tid; j < NB; j += 256) cur[j] = ghist[j * gridDim.x + b];
    __syncthreads();
    int s = b * EPB, e = min(s + EPB, E);
    for (int k = s + tid; k < e; k += 256) {
        unsigned hh = (unsigned)h[k];
        int pos = atomicAdd(&cur[hh >> 8], 1);
        stg[pos] = ((hh & 255u) << 18) | (unsigned)t[k];
    }
}

__global__ void finalize_kernel(const unsigned* __restrict__ stg, const int* __restrict__ bbase,
                                int* __restrict__ off, int* __restrict__ csr_t, int N, int E) {
    __shared__ int cnt[256];
    __shared__ int scn[256];
    int b = blockIdx.x, tid = threadIdx.x;
    int ebeg = bbase[b], eend = bbase[b + 1];
    cnt[tid] = 0;
    __syncthreads();
    for (int k = ebeg + tid; k < eend; k += 256)
        atomicAdd(&cnt[(stg[k] >> 18) & 255u], 1);
    __syncthreads();
    int v = cnt[tid];
    scn[tid] = v;
    __syncthreads();
    for (int o = 1; o < 256; o <<= 1) {
        int a = (tid >= o) ? scn[tid - o] : 0;
        __syncthreads();
        scn[tid] += a;
        __syncthreads();
    }
    int excl = scn[tid] - v;
    int gn = (b << 8) + tid;
    if (gn < N) off[gn] = ebeg + excl;
    if (b == 0 && tid == 0) off[N] = E;
    __syncthreads();
    cnt[tid] = excl;   // reuse as cursor
    __syncthreads();
    for (int k = ebeg + tid; k < eend; k += 256) {
        unsigned en = stg[k];
        int slot = atomicAdd(&cnt[(en >> 18) & 255u], 1);
        csr_t[ebeg + slot] = (int)(en & 0x3FFFFu);
    }
}

// bootstrap: prob=0.25 folded -> dcol0 = 0.5/sqrt(deg)
__global__ void dcol0_kernel(const int* __restrict__ off, float* __restrict__ dcol, int N) {
    int n = blockIdx.x * blockDim.x + threadIdx.x;
    if (n >= N) return;
    float v = 0.5f * rsqrtf((float)(off[n + 1] - off[n]));
    *(float4*)(dcol + (size_t)n * 4) = make_float4(v, v, v, v);
}

// ============ per-layer: xs = f16(x); invnx[n][f] = 1/max(||x_nf||,eps)
__global__ void prep_kernel(const float* __restrict__ x, u16* __restrict__ xs,
                            float* __restrict__ invnx, int total) {
    int i = blockIdx.x * blockDim.x + threadIdx.x;
    if (i >= total) return;
    float v = x[i];
    xs[i] = f2h(v);
    float s = v * v;
#pragma unroll
    for (int o = 8; o >= 1; o >>= 1) s += __shfl_xor(s, o);
    if ((i & 15) == 0) invnx[i >> 4] = 1.0f / fmaxf(sqrtf(s), 1e-12f);
}

// ============ fused message + routing + next-iteration softmax/dcol
// One 64-lane wave per node. lane l: g=l>>3 (8 edge slots), m=l&7 (col octet,
// one uint4 = 8 f16), f=m>>1. Loop1 fetches xs rows; the first 32 edges are
// stashed in LDS (16 KB/block, deg<=32 covers ~99.9% of nodes); loop2 reads
// LDS and recomputes tail = tanh(xs*invnx[t]) via packed f16 math.
// ACC: 0=none, 1=acc+=val, 2=acc=(acc+val)/3 (final mean)
template <bool UNI, bool WOUT, bool ROUTE, int ACC>
__global__ void message_kernel(const int* __restrict__ off, const int* __restrict__ csr_t,
                               float* __restrict__ Acsr, float* __restrict__ prob,
                               const u16* __restrict__ xs, const float* __restrict__ invnx,
                               const float* __restrict__ dcol_in, float* __restrict__ dcol_out,
                               float* __restrict__ out, float* __restrict__ acc, int N) {
    __shared__ uint4 cache[4][32][8];   // [wave][edge slot][col octet] = 16 KB
    int gid = blockIdx.x * blockDim.x + threadIdx.x;
    int n = gid >> 6;
    if (n >= N) return;
    int tid = threadIdx.x;
    int wid = tid >> 6;
    int l = tid & 63;
    int g = l >> 3;
    int m = l & 7;
    unsigned f = (unsigned)(m >> 1);
    int s = off[n], e = off[n + 1];
    unsigned moff = (unsigned)(m << 3);   // u16 index within the 64-wide row

    union U8 { uint4 u; f16 h[8]; h2 p[4]; };

    float a0 = 0.f, a1 = 0.f, a2 = 0.f, a3 = 0.f;
    float a4 = 0.f, a5 = 0.f, a6 = 0.f, a7 = 0.f;

    auto accum = [&](const U8& w1, const U8& w2, float p1, float p2) {
        a0 = fmaf(p1, (float)w1.h[0], a0); a1 = fmaf(p1, (float)w1.h[1], a1);
        a2 = fmaf(p1, (float)w1.h[2], a2); a3 = fmaf(p1, (float)w1.h[3], a3);
        a4 = fmaf(p1, (float)w1.h[4], a4); a5 = fmaf(p1, (float)w1.h[5], a5);
        a6 = fmaf(p1, (float)w1.h[6], a6); a7 = fmaf(p1, (float)w1.h[7], a7);
        a0 = fmaf(p2, (float)w2.h[0], a0); a1 = fmaf(p2, (float)w2.h[1], a1);
        a2 = fmaf(p2, (float)w2.h[2], a2); a3 = fmaf(p2, (float)w2.h[3], a3);
        a4 = fmaf(p2, (float)w2.h[4], a4); a5 = fmaf(p2, (float)w2.h[5], a5);
        a6 = fmaf(p2, (float)w2.h[6], a6); a7 = fmaf(p2, (float)w2.h[7], a7);
    };

    // loop1 trip: gather 16 edges; optionally stash rows into LDS slot sbase
    auto trip1 = [&](int kbase, int sbase) {
        int e1 = kbase + g, e2 = e1 + 8;
        bool v1 = e1 < e, v2 = e2 < e;
        unsigned c1 = (unsigned)(v1 ? e1 : s);
        unsigned c2 = (unsigned)(v2 ? e2 : s);
        unsigned t1 = (unsigned)csr_t[c1];
        unsigned t2 = (unsigned)csr_t[c2];
        float p1, p2;
        if (UNI) {
            p1 = dcol_in[t1 * 4u + f];
            p2 = dcol_in[t2 * 4u + f];
        } else {
            p1 = prob[c1 * 4u + f] * dcol_in[t1 * 4u + f];
            p2 = prob[c2 * 4u + f] * dcol_in[t2 * 4u + f];
        }
        p1 = v1 ? p1 : 0.f;
        p2 = v2 ? p2 : 0.f;
        U8 w1, w2;
        w1.u = *(const uint4*)(xs + (t1 << 6) + moff);
        w2.u = *(const uint4*)(xs + (t2 << 6) + moff);
        if (sbase >= 0) {
            cache[wid][sbase + g][m] = w1.u;
            cache[wid][sbase + g + 8][m] = w2.u;
        }
        accum(w1, w2, p1, p2);
    };

    trip1(s, 0);                                   // edges 0..15 -> LDS
    if (s + 16 < e) trip1(s + 16, 16);             // edges 16..31 -> LDS
    for (int k = s + 32; k < e; k += 16) trip1(k, -1);

    // combine the 8 edge slots -> every lane holds full sums for its 8 cols
#pragma unroll
    for (int o = 8; o <= 32; o <<= 1) {
        a0 += __shfl_xor(a0, o); a1 += __shfl_xor(a1, o);
        a2 += __shfl_xor(a2, o); a3 += __shfl_xor(a3, o);
        a4 += __shfl_xor(a4, o); a5 += __shfl_xor(a5, o);
        a6 += __shfl_xor(a6, o); a7 += __shfl_xor(a7, o);
    }

    if (WOUT || ACC != 0) {
        float dn = dcol_in[(unsigned)n * 4u + f];
        if (l < 8) {
            unsigned oidx = ((unsigned)n << 6) + moff;
            float4 lo = make_float4(a0 * dn, a1 * dn, a2 * dn, a3 * dn);
            float4 hi = make_float4(a4 * dn, a5 * dn, a6 * dn, a7 * dn);
            if (WOUT) {
                *(float4*)(out + oidx) = lo;
                *(float4*)(out + oidx + 4) = hi;
            }
            if (ACC == 1) {
                float4 c0 = *(const float4*)(acc + oidx);
                float4 c1 = *(const float4*)(acc + oidx + 4);
                *(float4*)(acc + oidx) =
                    make_float4(c0.x + lo.x, c0.y + lo.y, c0.z + lo.z, c0.w + lo.w);
                *(float4*)(acc + oidx + 4) =
                    make_float4(c1.x + hi.x, c1.y + hi.y, c1.z + hi.z, c1.w + hi.w);
            } else if (ACC == 2) {
                const float k3 = 1.0f / 3.0f;
                float4 c0 = *(const float4*)(acc + oidx);
                float4 c1 = *(const float4*)(acc + oidx + 4);
                *(float4*)(acc + oidx) =
                    make_float4((c0.x + lo.x) * k3, (c0.y + lo.y) * k3,
                                (c0.z + lo.z) * k3, (c0.w + lo.w) * k3);
                *(float4*)(acc + oidx + 4) =
                    make_float4((c1.x + hi.x) * k3, (c1.y + hi.y) * k3,
                                (c1.z + hi.z) * k3, (c1.w + hi.w) * k3);
            }
        }
    }
    if (!ROUTE) return;

    // head = l2norm per factor (dcol[n] scale-invariant); 16 cols = this lane's
    // 8 + partner lane's 8 (xor 1); pack head into f16x2 for dot2
    float ss = a0 * a0 + a1 * a1 + a2 * a2 + a3 * a3
             + a4 * a4 + a5 * a5 + a6 * a6 + a7 * a7;
    ss += __shfl_xor(ss, 1);
    float inv = 1.0f / fmaxf(sqrtf(ss), 1e-12f);
    h2 hp[4];
    hp[0] = h2{(f16)(a0 * inv), (f16)(a1 * inv)};
    hp[1] = h2{(f16)(a2 * inv), (f16)(a3 * inv)};
    hp[2] = h2{(f16)(a4 * inv), (f16)(a5 * inv)};
    hp[3] = h2{(f16)(a6 * inv), (f16)(a7 * inv)};
#ifndef USE_FDOT2
    float hv[8];
    hv[0] = a0 * inv; hv[1] = a1 * inv; hv[2] = a2 * inv; hv[3] = a3 * inv;
    hv[4] = a4 * inv; hv[5] = a5 * inv; hv[6] = a6 * inv; hv[7] = a7 * inv;
#endif

    const h2 C3 = {(f16)-0.030095f, (f16)-0.030095f};
    const h2 C2 = {(f16)0.124066f, (f16)0.124066f};
    const h2 C1 = {(f16)-0.332377f, (f16)-0.332377f};
    const h2 C0 = {(f16)1.0f, (f16)1.0f};

    // tail-dot: sum_i hp[i] . tanh_pk(xs_pair * iv)   (packed f16 poly)
    auto tdot = [&](const U8& w, float ivf) -> float {
        f16 ivh = (f16)ivf;
        h2 iv2 = {ivh, ivh};
        float d = 0.f;
#pragma unroll
        for (int i = 0; i < 4; ++i) {
            h2 a = w.p[i] * iv2;
            h2 aa = a * a;
            h2 t = aa * C3 + C2;
            t = aa * t + C1;
            t = aa * t + C0;
            h2 r = a * t;
#ifdef USE_FDOT2
            d = __builtin_amdgcn_fdot2(hp[i], r, d, false);
#else
            d = fmaf(hv[2 * i], (float)r.x, d);
            d = fmaf(hv[2 * i + 1], (float)r.y, d);
#endif
        }
        return d;
    };

    float rowsumf = 0.f;

    auto route = [&](int kbase, const U8& w1, const U8& w2,
                     unsigned t1, unsigned t2) {
        int e1 = kbase + g, e2 = e1 + 8;
        bool v1 = e1 < e, v2 = e2 < e;
        unsigned c1 = (unsigned)(v1 ? e1 : s);
        unsigned c2 = (unsigned)(v2 ? e2 : s);
        float iv1 = invnx[t1 * 4u + f];
        float iv2 = invnx[t2 * 4u + f];
        float d1 = tdot(w1, iv1);
        float d2 = tdot(w2, iv2);
        d1 += __shfl_xor(d1, 1);   // partner lane completes the 16-col dot
        d2 += __shfl_xor(d2, 1);
        unsigned ai1 = c1 * 4u + f;
        unsigned ai2 = c2 * 4u + f;
        float na1 = Acsr[ai1] + d1;
        float na2 = Acsr[ai2] + d2;
        // softmax over the 4 factors (xor 2 then xor 4 across f lanes)
        float ex1 = __expf(na1);
        float ex2 = __expf(na2);
        float se1 = ex1 + __shfl_xor(ex1, 2); se1 += __shfl_xor(se1, 4);
        float se2 = ex2 + __shfl_xor(ex2, 2); se2 += __shfl_xor(se2, 4);
        float p1 = ex1 * __builtin_amdgcn_rcpf(se1);
        float p2 = ex2 * __builtin_amdgcn_rcpf(se2);
        if ((m & 1) == 0) {
            if (v1) { Acsr[ai1] = na1; prob[ai1] = p1; }
            if (v2) { Acsr[ai2] = na2; prob[ai2] = p2; }
        }
        rowsumf += (v1 ? p1 : 0.f) + (v2 ? p2 : 0.f);
    };

    // loop2 trip reading rows from the LDS stash
    auto route_lds = [&](int kbase, int sbase) {
        int e1 = kbase + g, e2 = e1 + 8;
        unsigned c1 = (unsigned)((e1 < e) ? e1 : s);
        unsigned c2 = (unsigned)((e2 < e) ? e2 : s);
        unsigned t1 = (unsigned)csr_t[c1];
        unsigned t2 = (unsigned)csr_t[c2];
        U8 w1, w2;
        w1.u = cache[wid][sbase + g][m];
        w2.u = cache[wid][sbase + g + 8][m];
        route(kbase, w1, w2, t1, t2);
    };

    route_lds(s, 0);                               // edges 0..15 from LDS
    if (s + 16 < e) route_lds(s + 16, 16);         // edges 16..31 from LDS
    for (int k = s + 32; k < e; k += 16) {         // rare deg>32 overflow
        int e1 = k + g, e2 = e1 + 8;
        unsigned c1 = (unsigned)((e1 < e) ? e1 : s);
        unsigned c2 = (unsigned)((e2 < e) ? e2 : s);
        unsigned t1 = (unsigned)csr_t[c1];
        unsigned t2 = (unsigned)csr_t[c2];
        U8 w1, w2;
        w1.u = *(const uint4*)(xs + (t1 << 6) + moff);
        w2.u = *(const uint4*)(xs + (t2 << 6) + moff);
        route(k, w1, w2, t1, t2);
    }

    // sum over the 8 slots
    rowsumf += __shfl_xor(rowsumf, 8);
    rowsumf += __shfl_xor(rowsumf, 16);
    rowsumf += __shfl_xor(rowsumf, 32);
    if (l < 8 && (m & 1) == 0) dcol_out[(unsigned)n * 4u + f] = rsqrtf(rowsumf);
}

extern "C" void kernel_launch(void* const* d_in, const int* in_sizes, int n_in,
                              void* d_out, int out_size, void* d_ws, size_t ws_size,
                              hipStream_t stream) {
    const float* user_emb = (const float*)d_in[0];
    const float* item_emb = (const float*)d_in[1];
    const int* h = (const int*)d_in[2];
    const int* t = (const int*)d_in[3];

    const int nu_elems = in_sizes[0];
    const int ni_elems = in_sizes[1];
    const int total = nu_elems + ni_elems;   // N * 64
    const int N = total / DEMB;
    const int E = in_sizes[2];
    const int NB = (N + 255) >> 8;           // buckets (<= 1024)
    const int NBLK = 256;
    const int EPB = (E + NBLK - 1) / NBLK;

    float* acc = (float*)d_out;

    // ---- workspace layout ----
    float* x     = (float*)d_ws;                    // total f32
    float* out   = x + (size_t)total;               // total f32
    float* Acsr  = out + (size_t)total;             // 4E f32
    float* prob  = Acsr + (size_t)4 * E;            // 4E f32 (first E aliased as stg)
    float* dcolA = prob + (size_t)4 * E;            // 4N f32
    float* dcolB = dcolA + (size_t)4 * N;           // 4N f32
    float* invnx = dcolB + (size_t)4 * N;           // 4N f32
    u16* xs      = (u16*)(invnx + (size_t)4 * N);   // total u16 (f16 bits)
    int* ghist   = (int*)(xs + (size_t)total);      // NB*256
    int* btot    = ghist + (size_t)NB * 256;        // NB
    int* bbase   = btot + ((NB + 3) & ~3);          // NB+1
    int* off     = bbase + ((NB + 5) & ~3);         // N+1
    int* csr_t   = off + ((N + 4) & ~3);            // E
    unsigned* stg = (unsigned*)prob;                // E (time-disjoint with prob)

    const int BLK = 256;
    const int gE = (E + BLK - 1) / BLK;
    const int gTot = (total + BLK - 1) / BLK;
    const int gN = (N + BLK - 1) / BLK;
    const int gNodeWave = (N * 64 + BLK - 1) / BLK;

    concat_copy_kernel<<<gTot, BLK, 0, stream>>>(user_emb, item_emb, x, acc, nu_elems, total);

    // CSR build (deterministic, no contended global atomics)
    hist_kernel<<<NBLK, 256, 0, stream>>>(h, ghist, E, EPB, NB);
    btot_kernel<<<NB, 256, 0, stream>>>(ghist, btot);
    bscan_kernel<<<1, 1024, 0, stream>>>(btot, bbase, NB, E);
    bofs_kernel<<<NB, 256, 0, stream>>>(ghist, bbase);
    scatter_kernel<<<NBLK, 256, 0, stream>>>(h, t, ghist, stg, E, EPB, NB);
    finalize_kernel<<<NB, 256, 0, stream>>>(stg, bbase, off, csr_t, N, E);

    init_A_kernel<<<gE, BLK, 0, stream>>>((float4*)Acsr, E);
    dcol0_kernel<<<gN, BLK, 0, stream>>>(off, dcolA, N);

    // ---- layer 0 ----
    prep_kernel<<<gTot, BLK, 0, stream>>>(x, xs, invnx, total);
    message_kernel<true, false, true, 0><<<gNodeWave, BLK, 0, stream>>>(
        off, csr_t, Acsr, prob, xs, invnx, dcolA, dcolB, out, acc, N);
    message_kernel<false, true, true, 1><<<gNodeWave, BLK, 0, stream>>>(
        off, csr_t, Acsr, prob, xs, invnx, dcolB, dcolA, out, acc, N);

    // ---- layer 1 ----
    prep_kernel<<<gTot, BLK, 0, stream>>>(out, xs, invnx, total);
    message_kernel<false, false, true, 0><<<gNodeWave, BLK, 0, stream>>>(
        off, csr_t, Acsr, prob, xs, invnx, dcolA, dcolB, x, acc, N);
    message_kernel<false, false, false, 2><<<gNodeWave, BLK, 0, stream>>>(
        off, csr_t, Acsr, prob, xs, invnx, dcolB, dcolA, x, acc, N);
}